// Round 7
// baseline (456.928 us; speedup 1.0000x reference)
//
#include <hip/hip_runtime.h>
#include <hip/hip_fp16.h>
#include <cstdint>
#include <cstddef>

#define B_ 4
#define C_ 128
#define H_ 128
#define W_ 128
#define P_ (H_*W_)       // 16384
#define NH_ 8
#define NL_ 3
#define NP_ 4
#define HD_ 16
#define C2_ 64

// ---- workspace layout (float elements) ----
#define SZ_V      ((size_t)B_*NL_*P_*C_)          // region; v stored bf16 [b][l][h][p][hd]
#define OFF_V     ((size_t)0)
#define OFF_HID   (OFF_V + SZ_V)                   // hid [br][b][c][p]
#define SZ_HID    ((size_t)2*B_*C2_*P_)
#define OFF_MP    (OFF_HID + SZ_HID)               // out_pre [b][p][c]
#define SZ_MP     ((size_t)B_*NH_*P_*24)
#define OFF_MA    (OFF_MP + SZ_MP)
#define SZ_MA     ((size_t)B_*NH_*P_*12)
#define OFF_ST    (OFF_MA + SZ_MA)                 // GN stats [br][b][g][2]
#define SZ_ST     ((size_t)128)
#define OFF_BE    (OFF_ST + SZ_ST)                 // vp effective bias [l][128]
#define SZ_BE     ((size_t)(NL_*C_))

typedef short bf16x8 __attribute__((ext_vector_type(8)));
typedef float f32x4  __attribute__((ext_vector_type(4)));
#define MFMA16(a,b,c) __builtin_amdgcn_mfma_f32_16x16x32_bf16(a,b,c,0,0,0)

// split fp32 -> bf16 hi + bf16 lo (truncation; rem exact)
__device__ __forceinline__ void cvt8(const float* __restrict__ x, bf16x8& hi, bf16x8& lo) {
#pragma unroll
    for (int j = 0; j < 8; ++j) {
        unsigned ub = __float_as_uint(x[j]);
        hi[j] = (short)(ub >> 16);
        float rem = x[j] - __uint_as_float(ub & 0xffff0000u);
        lo[j] = (short)(__float_as_uint(rem) >> 16);
    }
}

// fp32 -> single bf16 round-nearest
__device__ __forceinline__ bf16x8 cvt8rn(const float* __restrict__ x) {
    bf16x8 r;
#pragma unroll
    for (int j = 0; j < 8; ++j) {
        unsigned u = __float_as_uint(x[j]);
        r[j] = (short)((u + 0x7fffu + ((u >> 16) & 1u)) >> 16);
    }
    return r;
}

__device__ __forceinline__ unsigned short f2bf_rn(float f) {
    unsigned u = __float_as_uint(f);
    return (unsigned short)((u + 0x7fffu + ((u >> 16) & 1u)) >> 16);
}
__device__ __forceinline__ float bflo(unsigned u) { return __uint_as_float(u << 16); }
__device__ __forceinline__ float bfhi(unsigned u) { return __uint_as_float(u & 0xffff0000u); }

__device__ __forceinline__ unsigned pkhalf2(float a, float b) {
    return (unsigned)__half_as_ushort(__float2half_rn(a))
         | ((unsigned)__half_as_ushort(__float2half_rn(b)) << 16);
}
__device__ __forceinline__ float hlo(unsigned u) { return __half2float(__ushort_as_half((unsigned short)u)); }
__device__ __forceinline__ float hhi(unsigned u) { return __half2float(__ushort_as_half((unsigned short)(u >> 16))); }

// ---------------------------------------------------------------------------
__global__ void k_prep(const float* __restrict__ vp_w, const float* __restrict__ vp_b,
                       const float* __restrict__ le, float* __restrict__ bias_eff,
                       float* __restrict__ stats)
{
    const int t = threadIdx.x;            // 384 threads
    if (t < 128) stats[t] = 0.f;
    const int l = t >> 7;
    const int o = t & 127;
    float d = vp_b[o];
    for (int k = 0; k < 128; ++k) d = fmaf(vp_w[o*128 + k], le[l*128 + k], d);
    bias_eff[l*128 + o] = d;
}

// ---------------------------------------------------------------------------
// MFMA value projection -> bf16 head-planar v [b][l][h][p][hd].
// LDS-staged input tile [128ch][66] (one bulk load, no redundant wave loads);
// B-operand single bf16-RN (2 MFMA per rt).
__global__ __launch_bounds__(256,4) void k_vproj(
    const float* __restrict__ vals, const float* __restrict__ vp_w,
    const float* __restrict__ bias_eff, unsigned short* __restrict__ v16)
{
    __shared__ float S[128*66];
    const int tid = threadIdx.x;
    const int wv = tid >> 6, l = tid & 63;
    const int lr = l & 15, lg = l >> 4;
    const int bl = blockIdx.y, lvl = bl % NL_;
    const int px0 = blockIdx.x * 64;
    const float* __restrict__ X = vals + (size_t)bl*C_*P_;

    // A fragments: rows oc = wv*32 + rt*16 + lr ; k = t*32 + lg*8 + j
    bf16x8 Ahi[2][4], Alo[2][4];
#pragma unroll
    for (int rt = 0; rt < 2; ++rt)
#pragma unroll
        for (int t = 0; t < 4; ++t) {
            const float* wr = vp_w + (size_t)(wv*32 + rt*16 + lr)*128 + t*32 + lg*8;
            float x8[8];
            float4 a = *(const float4*)wr, b = *(const float4*)(wr + 4);
            x8[0]=a.x; x8[1]=a.y; x8[2]=a.z; x8[3]=a.w;
            x8[4]=b.x; x8[5]=b.y; x8[6]=b.z; x8[7]=b.w;
            cvt8(x8, Ahi[rt][t], Alo[rt][t]);
        }

    // stage tile: coalesced global float4 -> LDS [ch][66]
    float4 st[8];
#pragma unroll
    for (int i = 0; i < 8; ++i) {
        const int slot = i*256 + tid;
        const int ch = slot >> 4, px4 = (slot & 15) * 4;
        st[i] = *(const float4*)(X + (size_t)ch*P_ + px0 + px4);
    }
#pragma unroll
    for (int i = 0; i < 8; ++i) {
        const int slot = i*256 + tid;
        const int ch = slot >> 4, px4 = (slot & 15) * 4;
        float2* d = (float2*)&S[ch*66 + px4];
        d[0] = make_float2(st[i].x, st[i].y);
        d[1] = make_float2(st[i].z, st[i].w);
    }
    __syncthreads();

    f32x4 acc[2][4];
#pragma unroll
    for (int rt = 0; rt < 2; ++rt)
#pragma unroll
        for (int c = 0; c < 4; ++c)
#pragma unroll
            for (int r = 0; r < 4; ++r) acc[rt][c][r] = 0.f;

#pragma unroll
    for (int s = 0; s < 16; ++s) {
        const int c = s >> 2, t = s & 3;
        float x8[8];
#pragma unroll
        for (int j = 0; j < 8; ++j) x8[j] = S[(t*32 + lg*8 + j)*66 + c*16 + lr];
        bf16x8 bb = cvt8rn(x8);
#pragma unroll
        for (int rt = 0; rt < 2; ++rt) {
            acc[rt][c] = MFMA16(Ahi[rt][t], bb, acc[rt][c]);
            acc[rt][c] = MFMA16(Alo[rt][t], bb, acc[rt][c]);
        }
    }

    const float* be = bias_eff + lvl*128;
#pragma unroll
    for (int c = 0; c < 4; ++c) {
        const int px = px0 + c*16 + lr;
#pragma unroll
        for (int rt = 0; rt < 2; ++rt) {
            const int h  = wv*2 + rt;
            const int oc = h*16 + lg*4;
            uint2 stv;
            stv.x = (unsigned)f2bf_rn(acc[rt][c][0] + be[oc+0])
                  | ((unsigned)f2bf_rn(acc[rt][c][1] + be[oc+1]) << 16);
            stv.y = (unsigned)f2bf_rn(acc[rt][c][2] + be[oc+2])
                  | ((unsigned)f2bf_rn(acc[rt][c][3] + be[oc+3]) << 16);
            *(uint2*)(v16 + (((size_t)bl*NH_ + h)*P_ + px)*16 + lg*4) = stv;
        }
    }
}

// ---------------------------------------------------------------------------
// MFMA conv1 (both branches): LDS-staged input tile, B single bf16-RN.
__global__ __launch_bounds__(256,4) void k_conv1(
    const float* __restrict__ q,
    const float* __restrict__ w_so, const float* __restrict__ b_so,
    const float* __restrict__ w_aw, const float* __restrict__ b_aw,
    float* __restrict__ hid, float* __restrict__ stats)
{
    __shared__ float S[128*66];
    const int tid = threadIdx.x;
    const int wv = tid >> 6, l = tid & 63;
    const int lr = l & 15, lg = l >> 4;
    const int b = blockIdx.y;
    const int br = wv >> 1, oc0 = (wv & 1) * 32;
    const float* __restrict__ W  = br ? w_aw : w_so;
    const float* __restrict__ bi = br ? b_aw : b_so;
    const float* __restrict__ X  = q + (size_t)b*C_*P_;
    const int px0 = blockIdx.x * 64;

    bf16x8 Ahi[2][4], Alo[2][4];
#pragma unroll
    for (int rt = 0; rt < 2; ++rt)
#pragma unroll
        for (int t = 0; t < 4; ++t) {
            const float* wr = W + (size_t)(oc0 + rt*16 + lr)*128 + t*32 + lg*8;
            float x8[8];
            float4 a = *(const float4*)wr, bb = *(const float4*)(wr + 4);
            x8[0]=a.x; x8[1]=a.y; x8[2]=a.z; x8[3]=a.w;
            x8[4]=bb.x; x8[5]=bb.y; x8[6]=bb.z; x8[7]=bb.w;
            cvt8(x8, Ahi[rt][t], Alo[rt][t]);
        }

    float4 st[8];
#pragma unroll
    for (int i = 0; i < 8; ++i) {
        const int slot = i*256 + tid;
        const int ch = slot >> 4, px4 = (slot & 15) * 4;
        st[i] = *(const float4*)(X + (size_t)ch*P_ + px0 + px4);
    }
#pragma unroll
    for (int i = 0; i < 8; ++i) {
        const int slot = i*256 + tid;
        const int ch = slot >> 4, px4 = (slot & 15) * 4;
        float2* d = (float2*)&S[ch*66 + px4];
        d[0] = make_float2(st[i].x, st[i].y);
        d[1] = make_float2(st[i].z, st[i].w);
    }
    __syncthreads();

    f32x4 acc[2][4];
#pragma unroll
    for (int rt = 0; rt < 2; ++rt)
#pragma unroll
        for (int c = 0; c < 4; ++c)
#pragma unroll
            for (int r = 0; r < 4; ++r) acc[rt][c][r] = 0.f;

#pragma unroll
    for (int s = 0; s < 16; ++s) {
        const int c = s >> 2, t = s & 3;
        float x8[8];
#pragma unroll
        for (int j = 0; j < 8; ++j) x8[j] = S[(t*32 + lg*8 + j)*66 + c*16 + lr];
        bf16x8 bb = cvt8rn(x8);
#pragma unroll
        for (int rt = 0; rt < 2; ++rt) {
            acc[rt][c] = MFMA16(Ahi[rt][t], bb, acc[rt][c]);
            acc[rt][c] = MFMA16(Alo[rt][t], bb, acc[rt][c]);
        }
    }

    float* hb = hid + ((size_t)(br*B_ + b)*C2_)*P_;
#pragma unroll
    for (int rt = 0; rt < 2; ++rt) {
        float s = 0.f, ss = 0.f;
#pragma unroll
        for (int c = 0; c < 4; ++c) {
            const int px = px0 + c*16 + lr;
#pragma unroll
            for (int r = 0; r < 4; ++r) {
                const int oc = oc0 + rt*16 + lg*4 + r;
                float v = acc[rt][c][r] + bi[oc];
                hb[(size_t)oc*P_ + px] = v;
                s += v; ss += v*v;
            }
        }
#pragma unroll
        for (int off = 16; off > 0; off >>= 1) {
            s  += __shfl_xor(s,  off, 64);
            ss += __shfl_xor(ss, off, 64);
        }
        if ((l & 31) == 0) {
            const int g = (oc0 + rt*16 + (l >> 4)*4) >> 3;
            atomicAdd(&stats[((br*B_ + b)*8 + g)*2 + 0], s);
            atomicAdd(&stats[((br*B_ + b)*8 + g)*2 + 1], ss);
        }
    }
}

// ---------------------------------------------------------------------------
// FUSED conv2 + sampling. fp16-packed LDS (39 KB) + launch_bounds(256,4)
// -> 4 blocks/CU. 16x4 pixel tiles + bijective XCD swizzle (kept from R5).
__global__ __launch_bounds__(256,4) void k_conv2s(
    const float* __restrict__ hid, const float* __restrict__ stats,
    const float* __restrict__ so_g, const float* __restrict__ so_be,
    const float* __restrict__ aw_g, const float* __restrict__ aw_be,
    const float* __restrict__ so_w2, const float* __restrict__ so_b2,
    const float* __restrict__ aw_w2, const float* __restrict__ aw_b2,
    const unsigned short* __restrict__ v16, float* __restrict__ out_pre)
{
    __shared__ float sc[2][64], sh[2][64];
    __shared__ unsigned SA16[96*66];      // offset pairs (ox,oy) fp16x2, row = ch/2
    __shared__ unsigned SB16[48*66];      // logit pairs fp16x2, row = ch/2
    const int tid = threadIdx.x;
    const int wv = tid >> 6, l = tid & 63;
    const int lr = l & 15, lg = l >> 4;

    const int lid = blockIdx.x + 256*blockIdx.y;
    const int swz = ((lid & 7) << 7) | (lid >> 3);
    const int b    = swz >> 8;
    const int tile = swz & 255;
    const int x0 = (tile & 7) * 16;
    const int y0 = (tile >> 3) * 4;

    if (tid < 128) {
        const int br = tid >> 6, c = tid & 63, g = c >> 3;
        const float ninv = 1.f/(8.f*(float)P_);
        float s  = stats[((br*B_ + b)*8 + g)*2 + 0];
        float ss = stats[((br*B_ + b)*8 + g)*2 + 1];
        float mu  = s*ninv;
        float var = ss*ninv - mu*mu;
        float rs  = rsqrtf(var + 1e-5f);
        float ga = br ? aw_g[c]  : so_g[c];
        float be = br ? aw_be[c] : so_be[c];
        sc[br][c] = ga*rs;
        sh[br][c] = be - mu*ga*rs;
    }
    __syncthreads();

    const int pxw = (y0 + wv)*W_ + x0 + lr;

    // ---- offset branch: 192 ch -> SA16 ----
    bf16x8 Bhi[2], Blo[2];
    {
        const float* hs = hid + ((size_t)(0*B_ + b)*C2_)*P_ + pxw;
#pragma unroll
        for (int t = 0; t < 2; ++t) {
            float x8[8];
#pragma unroll
            for (int j = 0; j < 8; ++j) {
                const int k = t*32 + lg*8 + j;
                x8[j] = fmaxf(fmaf(hs[(size_t)k*P_], sc[0][k], sh[0][k]), 0.f);
            }
            cvt8(x8, Bhi[t], Blo[t]);
        }
    }
#pragma unroll
    for (int tile2 = 0; tile2 < 12; ++tile2) {
        f32x4 acc; acc[0]=0.f; acc[1]=0.f; acc[2]=0.f; acc[3]=0.f;
#pragma unroll
        for (int t = 0; t < 2; ++t) {
            const float* wr = so_w2 + (size_t)(tile2*16 + lr)*64 + t*32 + lg*8;
            float x8[8];
            float4 a = *(const float4*)wr, bb = *(const float4*)(wr + 4);
            x8[0]=a.x; x8[1]=a.y; x8[2]=a.z; x8[3]=a.w;
            x8[4]=bb.x; x8[5]=bb.y; x8[6]=bb.z; x8[7]=bb.w;
            bf16x8 ahi, alo; cvt8(x8, ahi, alo);
            acc = MFMA16(ahi, Bhi[t], acc);
            acc = MFMA16(alo, Bhi[t], acc);
            acc = MFMA16(ahi, Blo[t], acc);
        }
#pragma unroll
        for (int rp = 0; rp < 2; ++rp) {
            const int ch = tile2*16 + lg*4 + 2*rp;
            SA16[(tile2*8 + lg*2 + rp)*66 + wv*16 + lr] =
                pkhalf2(acc[2*rp] + so_b2[ch], acc[2*rp+1] + so_b2[ch+1]);
        }
    }

    // ---- attn branch: 96 ch -> SB16 ----
    {
        const float* hs = hid + ((size_t)(1*B_ + b)*C2_)*P_ + pxw;
#pragma unroll
        for (int t = 0; t < 2; ++t) {
            float x8[8];
#pragma unroll
            for (int j = 0; j < 8; ++j) {
                const int k = t*32 + lg*8 + j;
                x8[j] = fmaxf(fmaf(hs[(size_t)k*P_], sc[1][k], sh[1][k]), 0.f);
            }
            cvt8(x8, Bhi[t], Blo[t]);
        }
    }
#pragma unroll
    for (int tile2 = 0; tile2 < 6; ++tile2) {
        f32x4 acc; acc[0]=0.f; acc[1]=0.f; acc[2]=0.f; acc[3]=0.f;
#pragma unroll
        for (int t = 0; t < 2; ++t) {
            const float* wr = aw_w2 + (size_t)(tile2*16 + lr)*64 + t*32 + lg*8;
            float x8[8];
            float4 a = *(const float4*)wr, bb = *(const float4*)(wr + 4);
            x8[0]=a.x; x8[1]=a.y; x8[2]=a.z; x8[3]=a.w;
            x8[4]=bb.x; x8[5]=bb.y; x8[6]=bb.z; x8[7]=bb.w;
            bf16x8 ahi, alo; cvt8(x8, ahi, alo);
            acc = MFMA16(ahi, Bhi[t], acc);
            acc = MFMA16(alo, Bhi[t], acc);
            acc = MFMA16(ahi, Blo[t], acc);
        }
#pragma unroll
        for (int rp = 0; rp < 2; ++rp) {
            const int ch = tile2*16 + lg*4 + 2*rp;
            SB16[(tile2*8 + lg*2 + rp)*66 + wv*16 + lr] =
                pkhalf2(acc[2*rp] + aw_b2[ch], acc[2*rp+1] + aw_b2[ch+1]);
        }
    }
    __syncthreads();

    // ---- sampling: 2 (px,head) units per thread ----
    const int hh  = tid >> 5;             // 0..7
    const int pl0 = (tid & 31) * 2;       // 0..62
#pragma unroll
    for (int up = 0; up < 2; ++up) {
        const int pl = pl0 + up;
        const int x  = x0 + (pl & 15);
        const int y  = y0 + (pl >> 4);
        const int p  = y*W_ + x;
        const float refx = (float)x * (1.f/(float)(W_-1));
        const float refy = (float)y * (1.f/(float)(H_-1));

        // softmax weights from packed logits
        float av[12];
#pragma unroll
        for (int k = 0; k < 6; ++k) {
            const unsigned w = SB16[(hh*6 + k)*66 + pl];
            av[2*k]   = hlo(w);
            av[2*k+1] = hhi(w);
        }
        float m = av[0];
#pragma unroll
        for (int s = 1; s < 12; ++s) m = fmaxf(m, av[s]);
        float sum = 0.f;
#pragma unroll
        for (int s = 0; s < 12; ++s) { av[s] = __expf(av[s]-m); sum += av[s]; }
        const float inv = 1.f/sum;

        unsigned off12[12];
#pragma unroll
        for (int s = 0; s < 12; ++s) off12[s] = SA16[(hh*12 + s)*66 + pl];

        float acc[16];
#pragma unroll
        for (int j = 0; j < 16; ++j) acc[j] = 0.f;

#pragma unroll
        for (int lv = 0; lv < NL_; ++lv) {
            const unsigned short* vb = v16 + (((size_t)(b*NL_ + lv)*NH_ + hh)*P_)*16;
#pragma unroll
            for (int pt = 0; pt < NP_; ++pt) {
                const int s = lv*4 + pt;
                const float ox = hlo(off12[s]), oy = hhi(off12[s]);
                float lx2 = fminf(fmaxf(refx + ox*(1.f/(float)W_), 0.f), 1.f);
                float ly2 = fminf(fmaxf(refy + oy*(1.f/(float)H_), 0.f), 1.f);
                float px = fminf(fmaxf(lx2*(float)W_ - 0.5f, 0.f), (float)(W_-1));
                float py = fminf(fmaxf(ly2*(float)H_ - 0.5f, 0.f), (float)(H_-1));
                float x0f = floorf(px), y0f = floorf(py);
                float wx = px - x0f, wy = py - y0f;
                int xi0 = (int)x0f, yi0 = (int)y0f;
                int xi1 = min(xi0+1, W_-1), yi1 = min(yi0+1, H_-1);
                const uint4* t00 = (const uint4*)(vb + (size_t)(yi0*W_ + xi0)*16);
                const uint4* t01 = (const uint4*)(vb + (size_t)(yi0*W_ + xi1)*16);
                const uint4* t10 = (const uint4*)(vb + (size_t)(yi1*W_ + xi0)*16);
                const uint4* t11 = (const uint4*)(vb + (size_t)(yi1*W_ + xi1)*16);
                uint4 q00a = t00[0], q00b = t00[1];
                uint4 q01a = t01[0], q01b = t01[1];
                uint4 q10a = t10[0], q10b = t10[1];
                uint4 q11a = t11[0], q11b = t11[1];
                const float a   = av[s]*inv;
                const float a11 = a*wx*wy;
                const float a10 = a*wy - a11;
                const float a01 = a*wx - a11;
                const float a00 = a - a01 - a10 - a11;
                const unsigned* u00 = (const unsigned*)&q00a;
                const unsigned* u01 = (const unsigned*)&q01a;
                const unsigned* u10 = (const unsigned*)&q10a;
                const unsigned* u11 = (const unsigned*)&q11a;
#pragma unroll
                for (int i = 0; i < 4; ++i) {
                    float r = acc[2*i];
                    r = fmaf(a00, bflo(u00[i]), r);
                    r = fmaf(a01, bflo(u01[i]), r);
                    r = fmaf(a10, bflo(u10[i]), r);
                    r = fmaf(a11, bflo(u11[i]), r);
                    acc[2*i] = r;
                    r = acc[2*i+1];
                    r = fmaf(a00, bfhi(u00[i]), r);
                    r = fmaf(a01, bfhi(u01[i]), r);
                    r = fmaf(a10, bfhi(u10[i]), r);
                    r = fmaf(a11, bfhi(u11[i]), r);
                    acc[2*i+1] = r;
                }
                const unsigned* v00 = (const unsigned*)&q00b;
                const unsigned* v01 = (const unsigned*)&q01b;
                const unsigned* v10 = (const unsigned*)&q10b;
                const unsigned* v11 = (const unsigned*)&q11b;
#pragma unroll
                for (int i = 0; i < 4; ++i) {
                    float r = acc[8 + 2*i];
                    r = fmaf(a00, bflo(v00[i]), r);
                    r = fmaf(a01, bflo(v01[i]), r);
                    r = fmaf(a10, bflo(v10[i]), r);
                    r = fmaf(a11, bflo(v11[i]), r);
                    acc[8 + 2*i] = r;
                    r = acc[8 + 2*i + 1];
                    r = fmaf(a00, bfhi(v00[i]), r);
                    r = fmaf(a01, bfhi(v01[i]), r);
                    r = fmaf(a10, bfhi(v10[i]), r);
                    r = fmaf(a11, bfhi(v11[i]), r);
                    acc[8 + 2*i + 1] = r;
                }
            }
        }
        float* op = out_pre + ((size_t)b*P_ + p)*C_ + hh*HD_;
#pragma unroll
        for (int i = 0; i < 4; ++i)
            *(float4*)(op + 4*i) = make_float4(acc[4*i], acc[4*i+1], acc[4*i+2], acc[4*i+3]);
    }
}

// ---------------------------------------------------------------------------
// MFMA final conv: out[b][oc][p] = op_w . out_pre[b][p][:] + op_b  (unchanged)
__global__ __launch_bounds__(256) void k_convout(
    const float* __restrict__ inp, const float* __restrict__ op_w,
    const float* __restrict__ op_b, float* __restrict__ out)
{
    const int tid = threadIdx.x;
    const int wv = tid >> 6, l = tid & 63;
    const int lr = l & 15, lg = l >> 4;
    const int b = blockIdx.y;
    const int px0 = blockIdx.x * 64;

    bf16x8 Ahi[2][4], Alo[2][4];
#pragma unroll
    for (int rt = 0; rt < 2; ++rt)
#pragma unroll
        for (int t = 0; t < 4; ++t) {
            const float* wr = op_w + (size_t)(wv*32 + rt*16 + lr)*128 + t*32 + lg*8;
            float x8[8];
            float4 a = *(const float4*)wr, bb = *(const float4*)(wr + 4);
            x8[0]=a.x; x8[1]=a.y; x8[2]=a.z; x8[3]=a.w;
            x8[4]=bb.x; x8[5]=bb.y; x8[6]=bb.z; x8[7]=bb.w;
            cvt8(x8, Ahi[rt][t], Alo[rt][t]);
        }

    f32x4 acc[2][4];
#pragma unroll
    for (int rt = 0; rt < 2; ++rt)
#pragma unroll
        for (int c = 0; c < 4; ++c)
#pragma unroll
            for (int r = 0; r < 4; ++r) acc[rt][c][r] = 0.f;

#pragma unroll
    for (int c = 0; c < 4; ++c) {
        const int px = px0 + c*16 + lr;
        const float* xb = inp + ((size_t)b*P_ + px)*C_;
#pragma unroll
        for (int t = 0; t < 4; ++t) {
            const float* xp = xb + t*32 + lg*8;
            float x8[8];
            float4 a = *(const float4*)xp, bb = *(const float4*)(xp + 4);
            x8[0]=a.x; x8[1]=a.y; x8[2]=a.z; x8[3]=a.w;
            x8[4]=bb.x; x8[5]=bb.y; x8[6]=bb.z; x8[7]=bb.w;
            bf16x8 bhi, blo; cvt8(x8, bhi, blo);
#pragma unroll
            for (int rt = 0; rt < 2; ++rt) {
                acc[rt][c] = MFMA16(Ahi[rt][t], bhi, acc[rt][c]);
                acc[rt][c] = MFMA16(Alo[rt][t], bhi, acc[rt][c]);
                acc[rt][c] = MFMA16(Ahi[rt][t], blo, acc[rt][c]);
            }
        }
    }

    float* ob = out + (size_t)b*C_*P_;
#pragma unroll
    for (int rt = 0; rt < 2; ++rt)
#pragma unroll
        for (int c = 0; c < 4; ++c) {
            const int px = px0 + c*16 + lr;
#pragma unroll
            for (int r = 0; r < 4; ++r) {
                const int oc = wv*32 + rt*16 + lg*4 + r;
                ob[(size_t)oc*P_ + px] = acc[rt][c][r] + op_b[oc];
            }
        }
}

// ---------------------------------------------------------------------------
extern "C" void kernel_launch(void* const* d_in, const int* in_sizes, int n_in,
                              void* d_out, int out_size, void* d_ws, size_t ws_size,
                              hipStream_t stream)
{
    const float* query = (const float*)d_in[0];
    // d_in[1] = keys : UNUSED by reference
    const float* values = (const float*)d_in[2];
    const float* so_w1 = (const float*)d_in[3];
    const float* so_b1 = (const float*)d_in[4];
    const float* so_g  = (const float*)d_in[5];
    const float* so_be = (const float*)d_in[6];
    const float* so_w2 = (const float*)d_in[7];
    const float* so_b2 = (const float*)d_in[8];
    const float* aw_w1 = (const float*)d_in[9];
    const float* aw_b1 = (const float*)d_in[10];
    const float* aw_g  = (const float*)d_in[11];
    const float* aw_be = (const float*)d_in[12];
    const float* aw_w2 = (const float*)d_in[13];
    const float* aw_b2 = (const float*)d_in[14];
    const float* vp_w  = (const float*)d_in[15];
    const float* vp_b  = (const float*)d_in[16];
    const float* op_w  = (const float*)d_in[17];
    const float* op_b  = (const float*)d_in[18];
    const float* le    = (const float*)d_in[19];

    float* ws      = (float*)d_ws;
    unsigned short* v16 = (unsigned short*)(ws + OFF_V);
    float* hid     = ws + OFF_HID;
    float* out_pre = ws + OFF_MP;
    float* stats   = ws + OFF_ST;
    float* be      = ws + OFF_BE;
    float* out     = (float*)d_out;

    k_prep<<<dim3(1), dim3(384), 0, stream>>>(vp_w, vp_b, le, be, stats);
    k_vproj<<<dim3(P_/64, B_*NL_), dim3(256), 0, stream>>>(values, vp_w, be, v16);
    k_conv1<<<dim3(P_/64, B_), dim3(256), 0, stream>>>(query, so_w1, so_b1, aw_w1, aw_b1, hid, stats);
    k_conv2s<<<dim3(256, B_), dim3(256), 0, stream>>>(hid, stats, so_g, so_be, aw_g, aw_be,
                                                      so_w2, so_b2, aw_w2, aw_b2, v16, out_pre);
    k_convout<<<dim3(P_/64, B_), dim3(256), 0, stream>>>(out_pre, op_w, op_b, out);
}

// Round 8
// 258.304 us; speedup vs baseline: 1.7690x; 1.7690x over previous
//
#include <hip/hip_runtime.h>
#include <hip/hip_fp16.h>
#include <cstdint>
#include <cstddef>

#define B_ 4
#define C_ 128
#define H_ 128
#define W_ 128
#define P_ (H_*W_)       // 16384
#define NH_ 8
#define NL_ 3
#define NP_ 4
#define HD_ 16
#define C2_ 64

// ---- workspace layout (float elements) ----
#define SZ_V      ((size_t)B_*NL_*P_*C_)          // region; v stored bf16 [b][l][h][p][hd]
#define OFF_V     ((size_t)0)
#define OFF_HID   (OFF_V + SZ_V)                   // hid [br][b][c][p]
#define SZ_HID    ((size_t)2*B_*C2_*P_)
#define OFF_MP    (OFF_HID + SZ_HID)               // out_pre [b][p][c]
#define SZ_MP     ((size_t)B_*NH_*P_*24)
#define OFF_MA    (OFF_MP + SZ_MP)
#define SZ_MA     ((size_t)B_*NH_*P_*12)
#define OFF_ST    (OFF_MA + SZ_MA)                 // GN stats [br][b][g][2]
#define SZ_ST     ((size_t)128)
#define OFF_BE    (OFF_ST + SZ_ST)                 // vp effective bias [l][128]
#define SZ_BE     ((size_t)(NL_*C_))

typedef short bf16x8 __attribute__((ext_vector_type(8)));
typedef float f32x4  __attribute__((ext_vector_type(4)));
#define MFMA16(a,b,c) __builtin_amdgcn_mfma_f32_16x16x32_bf16(a,b,c,0,0,0)

// split fp32 -> bf16 hi + bf16 lo (truncation; rem exact)
__device__ __forceinline__ void cvt8(const float* __restrict__ x, bf16x8& hi, bf16x8& lo) {
#pragma unroll
    for (int j = 0; j < 8; ++j) {
        unsigned ub = __float_as_uint(x[j]);
        hi[j] = (short)(ub >> 16);
        float rem = x[j] - __uint_as_float(ub & 0xffff0000u);
        lo[j] = (short)(__float_as_uint(rem) >> 16);
    }
}

// fp32 -> single bf16 round-nearest
__device__ __forceinline__ bf16x8 cvt8rn(const float* __restrict__ x) {
    bf16x8 r;
#pragma unroll
    for (int j = 0; j < 8; ++j) {
        unsigned u = __float_as_uint(x[j]);
        r[j] = (short)((u + 0x7fffu + ((u >> 16) & 1u)) >> 16);
    }
    return r;
}

__device__ __forceinline__ unsigned short f2bf_rn(float f) {
    unsigned u = __float_as_uint(f);
    return (unsigned short)((u + 0x7fffu + ((u >> 16) & 1u)) >> 16);
}
__device__ __forceinline__ float bflo(unsigned u) { return __uint_as_float(u << 16); }
__device__ __forceinline__ float bfhi(unsigned u) { return __uint_as_float(u & 0xffff0000u); }

__device__ __forceinline__ unsigned pkhalf2(float a, float b) {
    return (unsigned)__half_as_ushort(__float2half_rn(a))
         | ((unsigned)__half_as_ushort(__float2half_rn(b)) << 16);
}
__device__ __forceinline__ float hlo(unsigned u) { return __half2float(__ushort_as_half((unsigned short)u)); }
__device__ __forceinline__ float hhi(unsigned u) { return __half2float(__ushort_as_half((unsigned short)(u >> 16))); }

// ---------------------------------------------------------------------------
__global__ void k_prep(const float* __restrict__ vp_w, const float* __restrict__ vp_b,
                       const float* __restrict__ le, float* __restrict__ bias_eff,
                       float* __restrict__ stats)
{
    const int t = threadIdx.x;            // 384 threads
    if (t < 128) stats[t] = 0.f;
    const int l = t >> 7;
    const int o = t & 127;
    float d = vp_b[o];
    for (int k = 0; k < 128; ++k) d = fmaf(vp_w[o*128 + k], le[l*128 + k], d);
    bias_eff[l*128 + o] = d;
}

// ---------------------------------------------------------------------------
// MFMA value projection -> bf16 head-planar v [b][l][h][p][hd].
// LDS-staged input tile [128ch][66]; B single bf16-RN (2 MFMA per rt).
__global__ __launch_bounds__(256) void k_vproj(
    const float* __restrict__ vals, const float* __restrict__ vp_w,
    const float* __restrict__ bias_eff, unsigned short* __restrict__ v16)
{
    __shared__ float S[128*66];
    const int tid = threadIdx.x;
    const int wv = tid >> 6, l = tid & 63;
    const int lr = l & 15, lg = l >> 4;
    const int bl = blockIdx.y, lvl = bl % NL_;
    const int px0 = blockIdx.x * 64;
    const float* __restrict__ X = vals + (size_t)bl*C_*P_;

    // A fragments: rows oc = wv*32 + rt*16 + lr ; k = t*32 + lg*8 + j
    bf16x8 Ahi[2][4], Alo[2][4];
#pragma unroll
    for (int rt = 0; rt < 2; ++rt)
#pragma unroll
        for (int t = 0; t < 4; ++t) {
            const float* wr = vp_w + (size_t)(wv*32 + rt*16 + lr)*128 + t*32 + lg*8;
            float x8[8];
            float4 a = *(const float4*)wr, b = *(const float4*)(wr + 4);
            x8[0]=a.x; x8[1]=a.y; x8[2]=a.z; x8[3]=a.w;
            x8[4]=b.x; x8[5]=b.y; x8[6]=b.z; x8[7]=b.w;
            cvt8(x8, Ahi[rt][t], Alo[rt][t]);
        }

    // stage tile: coalesced global float4 -> LDS [ch][66]
    float4 st[8];
#pragma unroll
    for (int i = 0; i < 8; ++i) {
        const int slot = i*256 + tid;
        const int ch = slot >> 4, px4 = (slot & 15) * 4;
        st[i] = *(const float4*)(X + (size_t)ch*P_ + px0 + px4);
    }
#pragma unroll
    for (int i = 0; i < 8; ++i) {
        const int slot = i*256 + tid;
        const int ch = slot >> 4, px4 = (slot & 15) * 4;
        float2* d = (float2*)&S[ch*66 + px4];
        d[0] = make_float2(st[i].x, st[i].y);
        d[1] = make_float2(st[i].z, st[i].w);
    }
    __syncthreads();

    f32x4 acc[2][4];
#pragma unroll
    for (int rt = 0; rt < 2; ++rt)
#pragma unroll
        for (int c = 0; c < 4; ++c)
#pragma unroll
            for (int r = 0; r < 4; ++r) acc[rt][c][r] = 0.f;

#pragma unroll
    for (int s = 0; s < 16; ++s) {
        const int c = s >> 2, t = s & 3;
        float x8[8];
#pragma unroll
        for (int j = 0; j < 8; ++j) x8[j] = S[(t*32 + lg*8 + j)*66 + c*16 + lr];
        bf16x8 bb = cvt8rn(x8);
#pragma unroll
        for (int rt = 0; rt < 2; ++rt) {
            acc[rt][c] = MFMA16(Ahi[rt][t], bb, acc[rt][c]);
            acc[rt][c] = MFMA16(Alo[rt][t], bb, acc[rt][c]);
        }
    }

    const float* be = bias_eff + lvl*128;
#pragma unroll
    for (int c = 0; c < 4; ++c) {
        const int px = px0 + c*16 + lr;
#pragma unroll
        for (int rt = 0; rt < 2; ++rt) {
            const int h  = wv*2 + rt;
            const int oc = h*16 + lg*4;
            uint2 stv;
            stv.x = (unsigned)f2bf_rn(acc[rt][c][0] + be[oc+0])
                  | ((unsigned)f2bf_rn(acc[rt][c][1] + be[oc+1]) << 16);
            stv.y = (unsigned)f2bf_rn(acc[rt][c][2] + be[oc+2])
                  | ((unsigned)f2bf_rn(acc[rt][c][3] + be[oc+3]) << 16);
            *(uint2*)(v16 + (((size_t)bl*NH_ + h)*P_ + px)*16 + lg*4) = stv;
        }
    }
}

// ---------------------------------------------------------------------------
// MFMA conv1 (both branches): LDS-staged input tile, B single bf16-RN.
__global__ __launch_bounds__(256) void k_conv1(
    const float* __restrict__ q,
    const float* __restrict__ w_so, const float* __restrict__ b_so,
    const float* __restrict__ w_aw, const float* __restrict__ b_aw,
    float* __restrict__ hid, float* __restrict__ stats)
{
    __shared__ float S[128*66];
    const int tid = threadIdx.x;
    const int wv = tid >> 6, l = tid & 63;
    const int lr = l & 15, lg = l >> 4;
    const int b = blockIdx.y;
    const int br = wv >> 1, oc0 = (wv & 1) * 32;
    const float* __restrict__ W  = br ? w_aw : w_so;
    const float* __restrict__ bi = br ? b_aw : b_so;
    const float* __restrict__ X  = q + (size_t)b*C_*P_;
    const int px0 = blockIdx.x * 64;

    bf16x8 Ahi[2][4], Alo[2][4];
#pragma unroll
    for (int rt = 0; rt < 2; ++rt)
#pragma unroll
        for (int t = 0; t < 4; ++t) {
            const float* wr = W + (size_t)(oc0 + rt*16 + lr)*128 + t*32 + lg*8;
            float x8[8];
            float4 a = *(const float4*)wr, bb = *(const float4*)(wr + 4);
            x8[0]=a.x; x8[1]=a.y; x8[2]=a.z; x8[3]=a.w;
            x8[4]=bb.x; x8[5]=bb.y; x8[6]=bb.z; x8[7]=bb.w;
            cvt8(x8, Ahi[rt][t], Alo[rt][t]);
        }

    float4 st[8];
#pragma unroll
    for (int i = 0; i < 8; ++i) {
        const int slot = i*256 + tid;
        const int ch = slot >> 4, px4 = (slot & 15) * 4;
        st[i] = *(const float4*)(X + (size_t)ch*P_ + px0 + px4);
    }
#pragma unroll
    for (int i = 0; i < 8; ++i) {
        const int slot = i*256 + tid;
        const int ch = slot >> 4, px4 = (slot & 15) * 4;
        float2* d = (float2*)&S[ch*66 + px4];
        d[0] = make_float2(st[i].x, st[i].y);
        d[1] = make_float2(st[i].z, st[i].w);
    }
    __syncthreads();

    f32x4 acc[2][4];
#pragma unroll
    for (int rt = 0; rt < 2; ++rt)
#pragma unroll
        for (int c = 0; c < 4; ++c)
#pragma unroll
            for (int r = 0; r < 4; ++r) acc[rt][c][r] = 0.f;

#pragma unroll
    for (int s = 0; s < 16; ++s) {
        const int c = s >> 2, t = s & 3;
        float x8[8];
#pragma unroll
        for (int j = 0; j < 8; ++j) x8[j] = S[(t*32 + lg*8 + j)*66 + c*16 + lr];
        bf16x8 bb = cvt8rn(x8);
#pragma unroll
        for (int rt = 0; rt < 2; ++rt) {
            acc[rt][c] = MFMA16(Ahi[rt][t], bb, acc[rt][c]);
            acc[rt][c] = MFMA16(Alo[rt][t], bb, acc[rt][c]);
        }
    }

    float* hb = hid + ((size_t)(br*B_ + b)*C2_)*P_;
#pragma unroll
    for (int rt = 0; rt < 2; ++rt) {
        float s = 0.f, ss = 0.f;
#pragma unroll
        for (int c = 0; c < 4; ++c) {
            const int px = px0 + c*16 + lr;
#pragma unroll
            for (int r = 0; r < 4; ++r) {
                const int oc = oc0 + rt*16 + lg*4 + r;
                float v = acc[rt][c][r] + bi[oc];
                hb[(size_t)oc*P_ + px] = v;
                s += v; ss += v*v;
            }
        }
#pragma unroll
        for (int off = 16; off > 0; off >>= 1) {
            s  += __shfl_xor(s,  off, 64);
            ss += __shfl_xor(ss, off, 64);
        }
        if ((l & 31) == 0) {
            const int g = (oc0 + rt*16 + (l >> 4)*4) >> 3;
            atomicAdd(&stats[((br*B_ + b)*8 + g)*2 + 0], s);
            atomicAdd(&stats[((br*B_ + b)*8 + g)*2 + 1], ss);
        }
    }
}

// ---------------------------------------------------------------------------
// FUSED conv2 + sampling. fp16-packed LDS (39 KB) -> VGPR-limited 3 blocks/CU.
// 16x4 pixel tiles + bijective XCD swizzle.
__global__ __launch_bounds__(256) void k_conv2s(
    const float* __restrict__ hid, const float* __restrict__ stats,
    const float* __restrict__ so_g, const float* __restrict__ so_be,
    const float* __restrict__ aw_g, const float* __restrict__ aw_be,
    const float* __restrict__ so_w2, const float* __restrict__ so_b2,
    const float* __restrict__ aw_w2, const float* __restrict__ aw_b2,
    const unsigned short* __restrict__ v16, float* __restrict__ out_pre)
{
    __shared__ float sc[2][64], sh[2][64];
    __shared__ unsigned SA16[96*66];      // offset pairs (ox,oy) fp16x2, row = ch/2
    __shared__ unsigned SB16[48*66];      // logit pairs fp16x2, row = ch/2
    const int tid = threadIdx.x;
    const int wv = tid >> 6, l = tid & 63;
    const int lr = l & 15, lg = l >> 4;

    const int lid = blockIdx.x + 256*blockIdx.y;
    const int swz = ((lid & 7) << 7) | (lid >> 3);
    const int b    = swz >> 8;
    const int tile = swz & 255;
    const int x0 = (tile & 7) * 16;
    const int y0 = (tile >> 3) * 4;

    if (tid < 128) {
        const int br = tid >> 6, c = tid & 63, g = c >> 3;
        const float ninv = 1.f/(8.f*(float)P_);
        float s  = stats[((br*B_ + b)*8 + g)*2 + 0];
        float ss = stats[((br*B_ + b)*8 + g)*2 + 1];
        float mu  = s*ninv;
        float var = ss*ninv - mu*mu;
        float rs  = rsqrtf(var + 1e-5f);
        float ga = br ? aw_g[c]  : so_g[c];
        float be = br ? aw_be[c] : so_be[c];
        sc[br][c] = ga*rs;
        sh[br][c] = be - mu*ga*rs;
    }
    __syncthreads();

    const int pxw = (y0 + wv)*W_ + x0 + lr;

    // ---- offset branch: 192 ch -> SA16 ----
    bf16x8 Bhi[2], Blo[2];
    {
        const float* hs = hid + ((size_t)(0*B_ + b)*C2_)*P_ + pxw;
#pragma unroll
        for (int t = 0; t < 2; ++t) {
            float x8[8];
#pragma unroll
            for (int j = 0; j < 8; ++j) {
                const int k = t*32 + lg*8 + j;
                x8[j] = fmaxf(fmaf(hs[(size_t)k*P_], sc[0][k], sh[0][k]), 0.f);
            }
            cvt8(x8, Bhi[t], Blo[t]);
        }
    }
#pragma unroll
    for (int tile2 = 0; tile2 < 12; ++tile2) {
        f32x4 acc; acc[0]=0.f; acc[1]=0.f; acc[2]=0.f; acc[3]=0.f;
#pragma unroll
        for (int t = 0; t < 2; ++t) {
            const float* wr = so_w2 + (size_t)(tile2*16 + lr)*64 + t*32 + lg*8;
            float x8[8];
            float4 a = *(const float4*)wr, bb = *(const float4*)(wr + 4);
            x8[0]=a.x; x8[1]=a.y; x8[2]=a.z; x8[3]=a.w;
            x8[4]=bb.x; x8[5]=bb.y; x8[6]=bb.z; x8[7]=bb.w;
            bf16x8 ahi, alo; cvt8(x8, ahi, alo);
            acc = MFMA16(ahi, Bhi[t], acc);
            acc = MFMA16(alo, Bhi[t], acc);
            acc = MFMA16(ahi, Blo[t], acc);
        }
#pragma unroll
        for (int rp = 0; rp < 2; ++rp) {
            const int ch = tile2*16 + lg*4 + 2*rp;
            SA16[(tile2*8 + lg*2 + rp)*66 + wv*16 + lr] =
                pkhalf2(acc[2*rp] + so_b2[ch], acc[2*rp+1] + so_b2[ch+1]);
        }
    }

    // ---- attn branch: 96 ch -> SB16 ----
    {
        const float* hs = hid + ((size_t)(1*B_ + b)*C2_)*P_ + pxw;
#pragma unroll
        for (int t = 0; t < 2; ++t) {
            float x8[8];
#pragma unroll
            for (int j = 0; j < 8; ++j) {
                const int k = t*32 + lg*8 + j;
                x8[j] = fmaxf(fmaf(hs[(size_t)k*P_], sc[1][k], sh[1][k]), 0.f);
            }
            cvt8(x8, Bhi[t], Blo[t]);
        }
    }
#pragma unroll
    for (int tile2 = 0; tile2 < 6; ++tile2) {
        f32x4 acc; acc[0]=0.f; acc[1]=0.f; acc[2]=0.f; acc[3]=0.f;
#pragma unroll
        for (int t = 0; t < 2; ++t) {
            const float* wr = aw_w2 + (size_t)(tile2*16 + lr)*64 + t*32 + lg*8;
            float x8[8];
            float4 a = *(const float4*)wr, bb = *(const float4*)(wr + 4);
            x8[0]=a.x; x8[1]=a.y; x8[2]=a.z; x8[3]=a.w;
            x8[4]=bb.x; x8[5]=bb.y; x8[6]=bb.z; x8[7]=bb.w;
            bf16x8 ahi, alo; cvt8(x8, ahi, alo);
            acc = MFMA16(ahi, Bhi[t], acc);
            acc = MFMA16(alo, Bhi[t], acc);
            acc = MFMA16(ahi, Blo[t], acc);
        }
#pragma unroll
        for (int rp = 0; rp < 2; ++rp) {
            const int ch = tile2*16 + lg*4 + 2*rp;
            SB16[(tile2*8 + lg*2 + rp)*66 + wv*16 + lr] =
                pkhalf2(acc[2*rp] + aw_b2[ch], acc[2*rp+1] + aw_b2[ch+1]);
        }
    }
    __syncthreads();

    // ---- sampling: 2 (px,head) units per thread ----
    const int hh  = tid >> 5;             // 0..7
    const int pl0 = (tid & 31) * 2;       // 0..62
#pragma unroll
    for (int up = 0; up < 2; ++up) {
        const int pl = pl0 + up;
        const int x  = x0 + (pl & 15);
        const int y  = y0 + (pl >> 4);
        const int p  = y*W_ + x;
        const float refx = (float)x * (1.f/(float)(W_-1));
        const float refy = (float)y * (1.f/(float)(H_-1));

        float av[12];
#pragma unroll
        for (int k = 0; k < 6; ++k) {
            const unsigned w = SB16[(hh*6 + k)*66 + pl];
            av[2*k]   = hlo(w);
            av[2*k+1] = hhi(w);
        }
        float m = av[0];
#pragma unroll
        for (int s = 1; s < 12; ++s) m = fmaxf(m, av[s]);
        float sum = 0.f;
#pragma unroll
        for (int s = 0; s < 12; ++s) { av[s] = __expf(av[s]-m); sum += av[s]; }
        const float inv = 1.f/sum;

        unsigned off12[12];
#pragma unroll
        for (int s = 0; s < 12; ++s) off12[s] = SA16[(hh*12 + s)*66 + pl];

        float acc[16];
#pragma unroll
        for (int j = 0; j < 16; ++j) acc[j] = 0.f;

#pragma unroll
        for (int lv = 0; lv < NL_; ++lv) {
            const unsigned short* vb = v16 + (((size_t)(b*NL_ + lv)*NH_ + hh)*P_)*16;
#pragma unroll
            for (int pt = 0; pt < NP_; ++pt) {
                const int s = lv*4 + pt;
                const float ox = hlo(off12[s]), oy = hhi(off12[s]);
                float lx2 = fminf(fmaxf(refx + ox*(1.f/(float)W_), 0.f), 1.f);
                float ly2 = fminf(fmaxf(refy + oy*(1.f/(float)H_), 0.f), 1.f);
                float px = fminf(fmaxf(lx2*(float)W_ - 0.5f, 0.f), (float)(W_-1));
                float py = fminf(fmaxf(ly2*(float)H_ - 0.5f, 0.f), (float)(H_-1));
                float x0f = floorf(px), y0f = floorf(py);
                float wx = px - x0f, wy = py - y0f;
                int xi0 = (int)x0f, yi0 = (int)y0f;
                int xi1 = min(xi0+1, W_-1), yi1 = min(yi0+1, H_-1);
                const uint4* t00 = (const uint4*)(vb + (size_t)(yi0*W_ + xi0)*16);
                const uint4* t01 = (const uint4*)(vb + (size_t)(yi0*W_ + xi1)*16);
                const uint4* t10 = (const uint4*)(vb + (size_t)(yi1*W_ + xi0)*16);
                const uint4* t11 = (const uint4*)(vb + (size_t)(yi1*W_ + xi1)*16);
                uint4 q00a = t00[0], q00b = t00[1];
                uint4 q01a = t01[0], q01b = t01[1];
                uint4 q10a = t10[0], q10b = t10[1];
                uint4 q11a = t11[0], q11b = t11[1];
                const float a   = av[s]*inv;
                const float a11 = a*wx*wy;
                const float a10 = a*wy - a11;
                const float a01 = a*wx - a11;
                const float a00 = a - a01 - a10 - a11;
                const unsigned* u00 = (const unsigned*)&q00a;
                const unsigned* u01 = (const unsigned*)&q01a;
                const unsigned* u10 = (const unsigned*)&q10a;
                const unsigned* u11 = (const unsigned*)&q11a;
#pragma unroll
                for (int i = 0; i < 4; ++i) {
                    float r = acc[2*i];
                    r = fmaf(a00, bflo(u00[i]), r);
                    r = fmaf(a01, bflo(u01[i]), r);
                    r = fmaf(a10, bflo(u10[i]), r);
                    r = fmaf(a11, bflo(u11[i]), r);
                    acc[2*i] = r;
                    r = acc[2*i+1];
                    r = fmaf(a00, bfhi(u00[i]), r);
                    r = fmaf(a01, bfhi(u01[i]), r);
                    r = fmaf(a10, bfhi(u10[i]), r);
                    r = fmaf(a11, bfhi(u11[i]), r);
                    acc[2*i+1] = r;
                }
                const unsigned* v00 = (const unsigned*)&q00b;
                const unsigned* v01 = (const unsigned*)&q01b;
                const unsigned* v10 = (const unsigned*)&q10b;
                const unsigned* v11 = (const unsigned*)&q11b;
#pragma unroll
                for (int i = 0; i < 4; ++i) {
                    float r = acc[8 + 2*i];
                    r = fmaf(a00, bflo(v00[i]), r);
                    r = fmaf(a01, bflo(v01[i]), r);
                    r = fmaf(a10, bflo(v10[i]), r);
                    r = fmaf(a11, bflo(v11[i]), r);
                    acc[8 + 2*i] = r;
                    r = acc[8 + 2*i + 1];
                    r = fmaf(a00, bfhi(v00[i]), r);
                    r = fmaf(a01, bfhi(v01[i]), r);
                    r = fmaf(a10, bfhi(v10[i]), r);
                    r = fmaf(a11, bfhi(v11[i]), r);
                    acc[8 + 2*i + 1] = r;
                }
            }
        }
        float* op = out_pre + ((size_t)b*P_ + p)*C_ + hh*HD_;
#pragma unroll
        for (int i = 0; i < 4; ++i)
            *(float4*)(op + 4*i) = make_float4(acc[4*i], acc[4*i+1], acc[4*i+2], acc[4*i+3]);
    }
}

// ---------------------------------------------------------------------------
// MFMA final conv: out[b][oc][p] = op_w . out_pre[b][p][:] + op_b
__global__ __launch_bounds__(256) void k_convout(
    const float* __restrict__ inp, const float* __restrict__ op_w,
    const float* __restrict__ op_b, float* __restrict__ out)
{
    const int tid = threadIdx.x;
    const int wv = tid >> 6, l = tid & 63;
    const int lr = l & 15, lg = l >> 4;
    const int b = blockIdx.y;
    const int px0 = blockIdx.x * 64;

    bf16x8 Ahi[2][4], Alo[2][4];
#pragma unroll
    for (int rt = 0; rt < 2; ++rt)
#pragma unroll
        for (int t = 0; t < 4; ++t) {
            const float* wr = op_w + (size_t)(wv*32 + rt*16 + lr)*128 + t*32 + lg*8;
            float x8[8];
            float4 a = *(const float4*)wr, bb = *(const float4*)(wr + 4);
            x8[0]=a.x; x8[1]=a.y; x8[2]=a.z; x8[3]=a.w;
            x8[4]=bb.x; x8[5]=bb.y; x8[6]=bb.z; x8[7]=bb.w;
            cvt8(x8, Ahi[rt][t], Alo[rt][t]);
        }

    f32x4 acc[2][4];
#pragma unroll
    for (int rt = 0; rt < 2; ++rt)
#pragma unroll
        for (int c = 0; c < 4; ++c)
#pragma unroll
            for (int r = 0; r < 4; ++r) acc[rt][c][r] = 0.f;

#pragma unroll
    for (int c = 0; c < 4; ++c) {
        const int px = px0 + c*16 + lr;
        const float* xb = inp + ((size_t)b*P_ + px)*C_;
#pragma unroll
        for (int t = 0; t < 4; ++t) {
            const float* xp = xb + t*32 + lg*8;
            float x8[8];
            float4 a = *(const float4*)xp, bb = *(const float4*)(xp + 4);
            x8[0]=a.x; x8[1]=a.y; x8[2]=a.z; x8[3]=a.w;
            x8[4]=bb.x; x8[5]=bb.y; x8[6]=bb.z; x8[7]=bb.w;
            bf16x8 bhi, blo; cvt8(x8, bhi, blo);
#pragma unroll
            for (int rt = 0; rt < 2; ++rt) {
                acc[rt][c] = MFMA16(Ahi[rt][t], bhi, acc[rt][c]);
                acc[rt][c] = MFMA16(Alo[rt][t], bhi, acc[rt][c]);
                acc[rt][c] = MFMA16(Ahi[rt][t], blo, acc[rt][c]);
            }
        }
    }

    float* ob = out + (size_t)b*C_*P_;
#pragma unroll
    for (int rt = 0; rt < 2; ++rt)
#pragma unroll
        for (int c = 0; c < 4; ++c) {
            const int px = px0 + c*16 + lr;
#pragma unroll
            for (int r = 0; r < 4; ++r) {
                const int oc = wv*32 + rt*16 + lg*4 + r;
                ob[(size_t)oc*P_ + px] = acc[rt][c][r] + op_b[oc];
            }
        }
}

// ---------------------------------------------------------------------------
extern "C" void kernel_launch(void* const* d_in, const int* in_sizes, int n_in,
                              void* d_out, int out_size, void* d_ws, size_t ws_size,
                              hipStream_t stream)
{
    const float* query = (const float*)d_in[0];
    // d_in[1] = keys : UNUSED by reference
    const float* values = (const float*)d_in[2];
    const float* so_w1 = (const float*)d_in[3];
    const float* so_b1 = (const float*)d_in[4];
    const float* so_g  = (const float*)d_in[5];
    const float* so_be = (const float*)d_in[6];
    const float* so_w2 = (const float*)d_in[7];
    const float* so_b2 = (const float*)d_in[8];
    const float* aw_w1 = (const float*)d_in[9];
    const float* aw_b1 = (const float*)d_in[10];
    const float* aw_g  = (const float*)d_in[11];
    const float* aw_be = (const float*)d_in[12];
    const float* aw_w2 = (const float*)d_in[13];
    const float* aw_b2 = (const float*)d_in[14];
    const float* vp_w  = (const float*)d_in[15];
    const float* vp_b  = (const float*)d_in[16];
    const float* op_w  = (const float*)d_in[17];
    const float* op_b  = (const float*)d_in[18];
    const float* le    = (const float*)d_in[19];

    float* ws      = (float*)d_ws;
    unsigned short* v16 = (unsigned short*)(ws + OFF_V);
    float* hid     = ws + OFF_HID;
    float* out_pre = ws + OFF_MP;
    float* stats   = ws + OFF_ST;
    float* be      = ws + OFF_BE;
    float* out     = (float*)d_out;

    k_prep<<<dim3(1), dim3(384), 0, stream>>>(vp_w, vp_b, le, be, stats);
    k_vproj<<<dim3(P_/64, B_*NL_), dim3(256), 0, stream>>>(values, vp_w, be, v16);
    k_conv1<<<dim3(P_/64, B_), dim3(256), 0, stream>>>(query, so_w1, so_b1, aw_w1, aw_b1, hid, stats);
    k_conv2s<<<dim3(256, B_), dim3(256), 0, stream>>>(hid, stats, so_g, so_be, aw_g, aw_be,
                                                      so_w2, so_b2, aw_w2, aw_b2, v16, out_pre);
    k_convout<<<dim3(P_/64, B_), dim3(256), 0, stream>>>(out_pre, op_w, op_b, out);
}

// Round 9
// 227.803 us; speedup vs baseline: 2.0058x; 1.1339x over previous
//
#include <hip/hip_runtime.h>
#include <hip/hip_fp16.h>
#include <cstdint>
#include <cstddef>

#define B_ 4
#define C_ 128
#define H_ 128
#define W_ 128
#define P_ (H_*W_)       // 16384
#define NH_ 8
#define NL_ 3
#define NP_ 4
#define HD_ 16
#define C2_ 64

// ---- workspace layout (float elements) ----
#define SZ_V      ((size_t)B_*NL_*P_*C_)          // region; v stored bf16 [b][l][h][p][hd]
#define OFF_V     ((size_t)0)
#define OFF_HID   (OFF_V + SZ_V)                   // hid [br][b][c][p]
#define SZ_HID    ((size_t)2*B_*C2_*P_)
#define OFF_ST    (OFF_HID + SZ_HID)               // GN stats [br][b][g][2]
#define SZ_ST     ((size_t)128)
#define OFF_BE    (OFF_ST + SZ_ST)                 // vp effective bias [l][128]
#define SZ_BE     ((size_t)(NL_*C_))

typedef short bf16x8 __attribute__((ext_vector_type(8)));
typedef float f32x4  __attribute__((ext_vector_type(4)));
#define MFMA16(a,b,c) __builtin_amdgcn_mfma_f32_16x16x32_bf16(a,b,c,0,0,0)

// split fp32 -> bf16 hi + bf16 lo (truncation; rem exact)
__device__ __forceinline__ void cvt8(const float* __restrict__ x, bf16x8& hi, bf16x8& lo) {
#pragma unroll
    for (int j = 0; j < 8; ++j) {
        unsigned ub = __float_as_uint(x[j]);
        hi[j] = (short)(ub >> 16);
        float rem = x[j] - __uint_as_float(ub & 0xffff0000u);
        lo[j] = (short)(__float_as_uint(rem) >> 16);
    }
}

// fp32 -> single bf16 round-nearest
__device__ __forceinline__ bf16x8 cvt8rn(const float* __restrict__ x) {
    bf16x8 r;
#pragma unroll
    for (int j = 0; j < 8; ++j) {
        unsigned u = __float_as_uint(x[j]);
        r[j] = (short)((u + 0x7fffu + ((u >> 16) & 1u)) >> 16);
    }
    return r;
}

__device__ __forceinline__ unsigned short f2bf_rn(float f) {
    unsigned u = __float_as_uint(f);
    return (unsigned short)((u + 0x7fffu + ((u >> 16) & 1u)) >> 16);
}
__device__ __forceinline__ float bflo(unsigned u) { return __uint_as_float(u << 16); }
__device__ __forceinline__ float bfhi(unsigned u) { return __uint_as_float(u & 0xffff0000u); }

__device__ __forceinline__ unsigned pkhalf2(float a, float b) {
    return (unsigned)__half_as_ushort(__float2half_rn(a))
         | ((unsigned)__half_as_ushort(__float2half_rn(b)) << 16);
}
__device__ __forceinline__ float hlo(unsigned u) { return __half2float(__ushort_as_half((unsigned short)u)); }
__device__ __forceinline__ float hhi(unsigned u) { return __half2float(__ushort_as_half((unsigned short)(u >> 16))); }

// ---------------------------------------------------------------------------
__global__ void k_prep(const float* __restrict__ vp_w, const float* __restrict__ vp_b,
                       const float* __restrict__ le, float* __restrict__ bias_eff,
                       float* __restrict__ stats)
{
    const int t = threadIdx.x;            // 384 threads
    if (t < 128) stats[t] = 0.f;
    const int l = t >> 7;
    const int o = t & 127;
    float d = vp_b[o];
    for (int k = 0; k < 128; ++k) d = fmaf(vp_w[o*128 + k], le[l*128 + k], d);
    bias_eff[l*128 + o] = d;
}

// ---------------------------------------------------------------------------
// MFMA value projection -> bf16 head-planar v [b][l][h][p][hd].
// LDS-staged input tile [128ch][66]; B single bf16-RN (2 MFMA per rt).
__global__ __launch_bounds__(256) void k_vproj(
    const float* __restrict__ vals, const float* __restrict__ vp_w,
    const float* __restrict__ bias_eff, unsigned short* __restrict__ v16)
{
    __shared__ float S[128*66];
    const int tid = threadIdx.x;
    const int wv = tid >> 6, l = tid & 63;
    const int lr = l & 15, lg = l >> 4;
    const int bl = blockIdx.y, lvl = bl % NL_;
    const int px0 = blockIdx.x * 64;
    const float* __restrict__ X = vals + (size_t)bl*C_*P_;

    bf16x8 Ahi[2][4], Alo[2][4];
#pragma unroll
    for (int rt = 0; rt < 2; ++rt)
#pragma unroll
        for (int t = 0; t < 4; ++t) {
            const float* wr = vp_w + (size_t)(wv*32 + rt*16 + lr)*128 + t*32 + lg*8;
            float x8[8];
            float4 a = *(const float4*)wr, b = *(const float4*)(wr + 4);
            x8[0]=a.x; x8[1]=a.y; x8[2]=a.z; x8[3]=a.w;
            x8[4]=b.x; x8[5]=b.y; x8[6]=b.z; x8[7]=b.w;
            cvt8(x8, Ahi[rt][t], Alo[rt][t]);
        }

    float4 st[8];
#pragma unroll
    for (int i = 0; i < 8; ++i) {
        const int slot = i*256 + tid;
        const int ch = slot >> 4, px4 = (slot & 15) * 4;
        st[i] = *(const float4*)(X + (size_t)ch*P_ + px0 + px4);
    }
#pragma unroll
    for (int i = 0; i < 8; ++i) {
        const int slot = i*256 + tid;
        const int ch = slot >> 4, px4 = (slot & 15) * 4;
        float2* d = (float2*)&S[ch*66 + px4];
        d[0] = make_float2(st[i].x, st[i].y);
        d[1] = make_float2(st[i].z, st[i].w);
    }
    __syncthreads();

    f32x4 acc[2][4];
#pragma unroll
    for (int rt = 0; rt < 2; ++rt)
#pragma unroll
        for (int c = 0; c < 4; ++c)
#pragma unroll
            for (int r = 0; r < 4; ++r) acc[rt][c][r] = 0.f;

#pragma unroll
    for (int s = 0; s < 16; ++s) {
        const int c = s >> 2, t = s & 3;
        float x8[8];
#pragma unroll
        for (int j = 0; j < 8; ++j) x8[j] = S[(t*32 + lg*8 + j)*66 + c*16 + lr];
        bf16x8 bb = cvt8rn(x8);
#pragma unroll
        for (int rt = 0; rt < 2; ++rt) {
            acc[rt][c] = MFMA16(Ahi[rt][t], bb, acc[rt][c]);
            acc[rt][c] = MFMA16(Alo[rt][t], bb, acc[rt][c]);
        }
    }

    const float* be = bias_eff + lvl*128;
#pragma unroll
    for (int c = 0; c < 4; ++c) {
        const int px = px0 + c*16 + lr;
#pragma unroll
        for (int rt = 0; rt < 2; ++rt) {
            const int h  = wv*2 + rt;
            const int oc = h*16 + lg*4;
            uint2 stv;
            stv.x = (unsigned)f2bf_rn(acc[rt][c][0] + be[oc+0])
                  | ((unsigned)f2bf_rn(acc[rt][c][1] + be[oc+1]) << 16);
            stv.y = (unsigned)f2bf_rn(acc[rt][c][2] + be[oc+2])
                  | ((unsigned)f2bf_rn(acc[rt][c][3] + be[oc+3]) << 16);
            *(uint2*)(v16 + (((size_t)bl*NH_ + h)*P_ + px)*16 + lg*4) = stv;
        }
    }
}

// ---------------------------------------------------------------------------
// MFMA conv1 (both branches): LDS-staged input tile, B single bf16-RN.
__global__ __launch_bounds__(256) void k_conv1(
    const float* __restrict__ q,
    const float* __restrict__ w_so, const float* __restrict__ b_so,
    const float* __restrict__ w_aw, const float* __restrict__ b_aw,
    float* __restrict__ hid, float* __restrict__ stats)
{
    __shared__ float S[128*66];
    const int tid = threadIdx.x;
    const int wv = tid >> 6, l = tid & 63;
    const int lr = l & 15, lg = l >> 4;
    const int b = blockIdx.y;
    const int br = wv >> 1, oc0 = (wv & 1) * 32;
    const float* __restrict__ W  = br ? w_aw : w_so;
    const float* __restrict__ bi = br ? b_aw : b_so;
    const float* __restrict__ X  = q + (size_t)b*C_*P_;
    const int px0 = blockIdx.x * 64;

    bf16x8 Ahi[2][4], Alo[2][4];
#pragma unroll
    for (int rt = 0; rt < 2; ++rt)
#pragma unroll
        for (int t = 0; t < 4; ++t) {
            const float* wr = W + (size_t)(oc0 + rt*16 + lr)*128 + t*32 + lg*8;
            float x8[8];
            float4 a = *(const float4*)wr, bb = *(const float4*)(wr + 4);
            x8[0]=a.x; x8[1]=a.y; x8[2]=a.z; x8[3]=a.w;
            x8[4]=bb.x; x8[5]=bb.y; x8[6]=bb.z; x8[7]=bb.w;
            cvt8(x8, Ahi[rt][t], Alo[rt][t]);
        }

    float4 st[8];
#pragma unroll
    for (int i = 0; i < 8; ++i) {
        const int slot = i*256 + tid;
        const int ch = slot >> 4, px4 = (slot & 15) * 4;
        st[i] = *(const float4*)(X + (size_t)ch*P_ + px0 + px4);
    }
#pragma unroll
    for (int i = 0; i < 8; ++i) {
        const int slot = i*256 + tid;
        const int ch = slot >> 4, px4 = (slot & 15) * 4;
        float2* d = (float2*)&S[ch*66 + px4];
        d[0] = make_float2(st[i].x, st[i].y);
        d[1] = make_float2(st[i].z, st[i].w);
    }
    __syncthreads();

    f32x4 acc[2][4];
#pragma unroll
    for (int rt = 0; rt < 2; ++rt)
#pragma unroll
        for (int c = 0; c < 4; ++c)
#pragma unroll
            for (int r = 0; r < 4; ++r) acc[rt][c][r] = 0.f;

#pragma unroll
    for (int s = 0; s < 16; ++s) {
        const int c = s >> 2, t = s & 3;
        float x8[8];
#pragma unroll
        for (int j = 0; j < 8; ++j) x8[j] = S[(t*32 + lg*8 + j)*66 + c*16 + lr];
        bf16x8 bb = cvt8rn(x8);
#pragma unroll
        for (int rt = 0; rt < 2; ++rt) {
            acc[rt][c] = MFMA16(Ahi[rt][t], bb, acc[rt][c]);
            acc[rt][c] = MFMA16(Alo[rt][t], bb, acc[rt][c]);
        }
    }

    float* hb = hid + ((size_t)(br*B_ + b)*C2_)*P_;
#pragma unroll
    for (int rt = 0; rt < 2; ++rt) {
        float s = 0.f, ss = 0.f;
#pragma unroll
        for (int c = 0; c < 4; ++c) {
            const int px = px0 + c*16 + lr;
#pragma unroll
            for (int r = 0; r < 4; ++r) {
                const int oc = oc0 + rt*16 + lg*4 + r;
                float v = acc[rt][c][r] + bi[oc];
                hb[(size_t)oc*P_ + px] = v;
                s += v; ss += v*v;
            }
        }
#pragma unroll
        for (int off = 16; off > 0; off >>= 1) {
            s  += __shfl_xor(s,  off, 64);
            ss += __shfl_xor(ss, off, 64);
        }
        if ((l & 31) == 0) {
            const int g = (oc0 + rt*16 + (l >> 4)*4) >> 3;
            atomicAdd(&stats[((br*B_ + b)*8 + g)*2 + 0], s);
            atomicAdd(&stats[((br*B_ + b)*8 + g)*2 + 1], ss);
        }
    }
}

// ---------------------------------------------------------------------------
// FUSED conv2 + sampling + FINAL CONV. Three phases:
//   1) GN+ReLU -> MFMA second conv (both branches) -> fp16-packed LDS
//   2) per-(px,head) clip + softmax + bilinear gather -> OUT tile in LDS
//   3) MFMA final conv (op_w) from OUT tile -> global out (channel-major)
// 16x4 pixel tiles + bijective XCD swizzle. OUT[64][133] unions SA16/SB16.
__global__ __launch_bounds__(256) void k_conv2s(
    const float* __restrict__ hid, const float* __restrict__ stats,
    const float* __restrict__ so_g, const float* __restrict__ so_be,
    const float* __restrict__ aw_g, const float* __restrict__ aw_be,
    const float* __restrict__ so_w2, const float* __restrict__ so_b2,
    const float* __restrict__ aw_w2, const float* __restrict__ aw_b2,
    const unsigned short* __restrict__ v16,
    const float* __restrict__ op_w, const float* __restrict__ op_b,
    float* __restrict__ outg)
{
    __shared__ float sc[2][64], sh[2][64];
    __shared__ unsigned SAB[96*66 + 48*66];   // 38016 B; phase1/2: SA16+SB16, phase3: OUT[64][133]
    unsigned* SA16 = SAB;
    unsigned* SB16 = SAB + 96*66;
    float*    OUT  = (float*)SAB;
    const int tid = threadIdx.x;
    const int wv = tid >> 6, l = tid & 63;
    const int lr = l & 15, lg = l >> 4;

    const int lid = blockIdx.x + 256*blockIdx.y;
    const int swz = ((lid & 7) << 7) | (lid >> 3);
    const int b    = swz >> 8;
    const int tile = swz & 255;
    const int x0 = (tile & 7) * 16;
    const int y0 = (tile >> 3) * 4;

    if (tid < 128) {
        const int br = tid >> 6, c = tid & 63, g = c >> 3;
        const float ninv = 1.f/(8.f*(float)P_);
        float s  = stats[((br*B_ + b)*8 + g)*2 + 0];
        float ss = stats[((br*B_ + b)*8 + g)*2 + 1];
        float mu  = s*ninv;
        float var = ss*ninv - mu*mu;
        float rs  = rsqrtf(var + 1e-5f);
        float ga = br ? aw_g[c]  : so_g[c];
        float be = br ? aw_be[c] : so_be[c];
        sc[br][c] = ga*rs;
        sh[br][c] = be - mu*ga*rs;
    }
    __syncthreads();

    const int pxw = (y0 + wv)*W_ + x0 + lr;

    // ---- phase 1a: offset branch 192 ch -> SA16 ----
    bf16x8 Bhi[2], Blo[2];
    {
        const float* hs = hid + ((size_t)(0*B_ + b)*C2_)*P_ + pxw;
#pragma unroll
        for (int t = 0; t < 2; ++t) {
            float x8[8];
#pragma unroll
            for (int j = 0; j < 8; ++j) {
                const int k = t*32 + lg*8 + j;
                x8[j] = fmaxf(fmaf(hs[(size_t)k*P_], sc[0][k], sh[0][k]), 0.f);
            }
            cvt8(x8, Bhi[t], Blo[t]);
        }
    }
#pragma unroll
    for (int tile2 = 0; tile2 < 12; ++tile2) {
        f32x4 acc; acc[0]=0.f; acc[1]=0.f; acc[2]=0.f; acc[3]=0.f;
#pragma unroll
        for (int t = 0; t < 2; ++t) {
            const float* wr = so_w2 + (size_t)(tile2*16 + lr)*64 + t*32 + lg*8;
            float x8[8];
            float4 a = *(const float4*)wr, bb = *(const float4*)(wr + 4);
            x8[0]=a.x; x8[1]=a.y; x8[2]=a.z; x8[3]=a.w;
            x8[4]=bb.x; x8[5]=bb.y; x8[6]=bb.z; x8[7]=bb.w;
            bf16x8 ahi, alo; cvt8(x8, ahi, alo);
            acc = MFMA16(ahi, Bhi[t], acc);
            acc = MFMA16(alo, Bhi[t], acc);
            acc = MFMA16(ahi, Blo[t], acc);
        }
#pragma unroll
        for (int rp = 0; rp < 2; ++rp) {
            const int ch = tile2*16 + lg*4 + 2*rp;
            SA16[(tile2*8 + lg*2 + rp)*66 + wv*16 + lr] =
                pkhalf2(acc[2*rp] + so_b2[ch], acc[2*rp+1] + so_b2[ch+1]);
        }
    }

    // ---- phase 1b: attn branch 96 ch -> SB16 ----
    {
        const float* hs = hid + ((size_t)(1*B_ + b)*C2_)*P_ + pxw;
#pragma unroll
        for (int t = 0; t < 2; ++t) {
            float x8[8];
#pragma unroll
            for (int j = 0; j < 8; ++j) {
                const int k = t*32 + lg*8 + j;
                x8[j] = fmaxf(fmaf(hs[(size_t)k*P_], sc[1][k], sh[1][k]), 0.f);
            }
            cvt8(x8, Bhi[t], Blo[t]);
        }
    }
#pragma unroll
    for (int tile2 = 0; tile2 < 6; ++tile2) {
        f32x4 acc; acc[0]=0.f; acc[1]=0.f; acc[2]=0.f; acc[3]=0.f;
#pragma unroll
        for (int t = 0; t < 2; ++t) {
            const float* wr = aw_w2 + (size_t)(tile2*16 + lr)*64 + t*32 + lg*8;
            float x8[8];
            float4 a = *(const float4*)wr, bb = *(const float4*)(wr + 4);
            x8[0]=a.x; x8[1]=a.y; x8[2]=a.z; x8[3]=a.w;
            x8[4]=bb.x; x8[5]=bb.y; x8[6]=bb.z; x8[7]=bb.w;
            bf16x8 ahi, alo; cvt8(x8, ahi, alo);
            acc = MFMA16(ahi, Bhi[t], acc);
            acc = MFMA16(alo, Bhi[t], acc);
            acc = MFMA16(ahi, Blo[t], acc);
        }
#pragma unroll
        for (int rp = 0; rp < 2; ++rp) {
            const int ch = tile2*16 + lg*4 + 2*rp;
            SB16[(tile2*8 + lg*2 + rp)*66 + wv*16 + lr] =
                pkhalf2(acc[2*rp] + aw_b2[ch], acc[2*rp+1] + aw_b2[ch+1]);
        }
    }
    __syncthreads();

    // ---- phase 2: sampling. Preload BOTH units' meta from LDS first (SAB is
    // overwritten by OUT below), then barrier, then gather + write OUT tile.
    const int hh  = tid >> 5;             // 0..7
    const int pl0 = (tid & 31) * 2;       // 0..62

    unsigned off12[2][12];
    float    aw12[2][12];
#pragma unroll
    for (int up = 0; up < 2; ++up) {
        const int pl = pl0 + up;
        float av[12];
#pragma unroll
        for (int k = 0; k < 6; ++k) {
            const unsigned w = SB16[(hh*6 + k)*66 + pl];
            av[2*k]   = hlo(w);
            av[2*k+1] = hhi(w);
        }
        float m = av[0];
#pragma unroll
        for (int s = 1; s < 12; ++s) m = fmaxf(m, av[s]);
        float sum = 0.f;
#pragma unroll
        for (int s = 0; s < 12; ++s) { av[s] = __expf(av[s]-m); sum += av[s]; }
        const float inv = 1.f/sum;
#pragma unroll
        for (int s = 0; s < 12; ++s) aw12[up][s] = av[s]*inv;
#pragma unroll
        for (int s = 0; s < 12; ++s) off12[up][s] = SA16[(hh*12 + s)*66 + pl];
    }
    __syncthreads();   // all SA16/SB16 reads done; SAB is now OUT

#pragma unroll
    for (int up = 0; up < 2; ++up) {
        const int pl = pl0 + up;
        const int x  = x0 + (pl & 15);
        const int y  = y0 + (pl >> 4);
        const float refx = (float)x * (1.f/(float)(W_-1));
        const float refy = (float)y * (1.f/(float)(H_-1));

        float acc[16];
#pragma unroll
        for (int j = 0; j < 16; ++j) acc[j] = 0.f;

#pragma unroll
        for (int lv = 0; lv < NL_; ++lv) {
            const unsigned short* vb = v16 + (((size_t)(b*NL_ + lv)*NH_ + hh)*P_)*16;
#pragma unroll
            for (int pt = 0; pt < NP_; ++pt) {
                const int s = lv*4 + pt;
                const float ox = hlo(off12[up][s]), oy = hhi(off12[up][s]);
                float lx2 = fminf(fmaxf(refx + ox*(1.f/(float)W_), 0.f), 1.f);
                float ly2 = fminf(fmaxf(refy + oy*(1.f/(float)H_), 0.f), 1.f);
                float px = fminf(fmaxf(lx2*(float)W_ - 0.5f, 0.f), (float)(W_-1));
                float py = fminf(fmaxf(ly2*(float)H_ - 0.5f, 0.f), (float)(H_-1));
                float x0f = floorf(px), y0f = floorf(py);
                float wx = px - x0f, wy = py - y0f;
                int xi0 = (int)x0f, yi0 = (int)y0f;
                int xi1 = min(xi0+1, W_-1), yi1 = min(yi0+1, H_-1);
                const uint4* t00 = (const uint4*)(vb + (size_t)(yi0*W_ + xi0)*16);
                const uint4* t01 = (const uint4*)(vb + (size_t)(yi0*W_ + xi1)*16);
                const uint4* t10 = (const uint4*)(vb + (size_t)(yi1*W_ + xi0)*16);
                const uint4* t11 = (const uint4*)(vb + (size_t)(yi1*W_ + xi1)*16);
                uint4 q00a = t00[0], q00b = t00[1];
                uint4 q01a = t01[0], q01b = t01[1];
                uint4 q10a = t10[0], q10b = t10[1];
                uint4 q11a = t11[0], q11b = t11[1];
                const float a   = aw12[up][s];
                const float a11 = a*wx*wy;
                const float a10 = a*wy - a11;
                const float a01 = a*wx - a11;
                const float a00 = a - a01 - a10 - a11;
                const unsigned* u00 = (const unsigned*)&q00a;
                const unsigned* u01 = (const unsigned*)&q01a;
                const unsigned* u10 = (const unsigned*)&q10a;
                const unsigned* u11 = (const unsigned*)&q11a;
#pragma unroll
                for (int i = 0; i < 4; ++i) {
                    float r = acc[2*i];
                    r = fmaf(a00, bflo(u00[i]), r);
                    r = fmaf(a01, bflo(u01[i]), r);
                    r = fmaf(a10, bflo(u10[i]), r);
                    r = fmaf(a11, bflo(u11[i]), r);
                    acc[2*i] = r;
                    r = acc[2*i+1];
                    r = fmaf(a00, bfhi(u00[i]), r);
                    r = fmaf(a01, bfhi(u01[i]), r);
                    r = fmaf(a10, bfhi(u10[i]), r);
                    r = fmaf(a11, bfhi(u11[i]), r);
                    acc[2*i+1] = r;
                }
                const unsigned* v00 = (const unsigned*)&q00b;
                const unsigned* v01 = (const unsigned*)&q01b;
                const unsigned* v10 = (const unsigned*)&q10b;
                const unsigned* v11 = (const unsigned*)&q11b;
#pragma unroll
                for (int i = 0; i < 4; ++i) {
                    float r = acc[8 + 2*i];
                    r = fmaf(a00, bflo(v00[i]), r);
                    r = fmaf(a01, bflo(v01[i]), r);
                    r = fmaf(a10, bflo(v10[i]), r);
                    r = fmaf(a11, bflo(v11[i]), r);
                    acc[8 + 2*i] = r;
                    r = acc[8 + 2*i + 1];
                    r = fmaf(a00, bfhi(v00[i]), r);
                    r = fmaf(a01, bfhi(v01[i]), r);
                    r = fmaf(a10, bfhi(v10[i]), r);
                    r = fmaf(a11, bfhi(v11[i]), r);
                    acc[8 + 2*i + 1] = r;
                }
            }
        }
        // write this unit's 16 channels into the OUT tile [pl][133]
        float* dst = OUT + pl*133 + hh*HD_;
#pragma unroll
        for (int i = 0; i < 4; ++i)
            *(float4*)(dst + 4*i) = make_float4(acc[4*i], acc[4*i+1], acc[4*i+2], acc[4*i+3]);
    }
    __syncthreads();   // OUT tile complete

    // ---- phase 3: final conv from OUT tile -> global out (channel-major) ----
    bf16x8 Ohi[2][4], Olo[2][4];
#pragma unroll
    for (int rt = 0; rt < 2; ++rt)
#pragma unroll
        for (int t = 0; t < 4; ++t) {
            const float* wr = op_w + (size_t)(wv*32 + rt*16 + lr)*128 + t*32 + lg*8;
            float x8[8];
            float4 a = *(const float4*)wr, bb = *(const float4*)(wr + 4);
            x8[0]=a.x; x8[1]=a.y; x8[2]=a.z; x8[3]=a.w;
            x8[4]=bb.x; x8[5]=bb.y; x8[6]=bb.z; x8[7]=bb.w;
            cvt8(x8, Ohi[rt][t], Olo[rt][t]);
        }

    f32x4 oacc[2][4];
#pragma unroll
    for (int rt = 0; rt < 2; ++rt)
#pragma unroll
        for (int c = 0; c < 4; ++c)
#pragma unroll
            for (int r = 0; r < 4; ++r) oacc[rt][c][r] = 0.f;

#pragma unroll
    for (int s = 0; s < 16; ++s) {
        const int c = s >> 2, t = s & 3;
        float x8[8];
#pragma unroll
        for (int j = 0; j < 8; ++j) x8[j] = OUT[(c*16 + lr)*133 + t*32 + lg*8 + j];
        bf16x8 bhi, blo; cvt8(x8, bhi, blo);
#pragma unroll
        for (int rt = 0; rt < 2; ++rt) {
            oacc[rt][c] = MFMA16(Ohi[rt][t], bhi, oacc[rt][c]);
            oacc[rt][c] = MFMA16(Olo[rt][t], bhi, oacc[rt][c]);
            oacc[rt][c] = MFMA16(Ohi[rt][t], blo, oacc[rt][c]);
        }
    }

    float* ob = outg + (size_t)b*C_*P_;
#pragma unroll
    for (int rt = 0; rt < 2; ++rt)
#pragma unroll
        for (int c = 0; c < 4; ++c) {
            const int p = (y0 + c)*W_ + x0 + lr;   // pl = c*16 + lr
#pragma unroll
            for (int r = 0; r < 4; ++r) {
                const int oc = wv*32 + rt*16 + lg*4 + r;
                ob[(size_t)oc*P_ + p] = oacc[rt][c][r] + op_b[oc];
            }
        }
}

// ---------------------------------------------------------------------------
extern "C" void kernel_launch(void* const* d_in, const int* in_sizes, int n_in,
                              void* d_out, int out_size, void* d_ws, size_t ws_size,
                              hipStream_t stream)
{
    const float* query = (const float*)d_in[0];
    // d_in[1] = keys : UNUSED by reference
    const float* values = (const float*)d_in[2];
    const float* so_w1 = (const float*)d_in[3];
    const float* so_b1 = (const float*)d_in[4];
    const float* so_g  = (const float*)d_in[5];
    const float* so_be = (const float*)d_in[6];
    const float* so_w2 = (const float*)d_in[7];
    const float* so_b2 = (const float*)d_in[8];
    const float* aw_w1 = (const float*)d_in[9];
    const float* aw_b1 = (const float*)d_in[10];
    const float* aw_g  = (const float*)d_in[11];
    const float* aw_be = (const float*)d_in[12];
    const float* aw_w2 = (const float*)d_in[13];
    const float* aw_b2 = (const float*)d_in[14];
    const float* vp_w  = (const float*)d_in[15];
    const float* vp_b  = (const float*)d_in[16];
    const float* op_w  = (const float*)d_in[17];
    const float* op_b  = (const float*)d_in[18];
    const float* le    = (const float*)d_in[19];

    float* ws      = (float*)d_ws;
    unsigned short* v16 = (unsigned short*)(ws + OFF_V);
    float* hid     = ws + OFF_HID;
    float* stats   = ws + OFF_ST;
    float* be      = ws + OFF_BE;
    float* out     = (float*)d_out;

    k_prep<<<dim3(1), dim3(384), 0, stream>>>(vp_w, vp_b, le, be, stats);
    k_vproj<<<dim3(P_/64, B_*NL_), dim3(256), 0, stream>>>(values, vp_w, be, v16);
    k_conv1<<<dim3(P_/64, B_), dim3(256), 0, stream>>>(query, so_w1, so_b1, aw_w1, aw_b1, hid, stats);
    k_conv2s<<<dim3(256, B_), dim3(256), 0, stream>>>(hid, stats, so_g, so_be, aw_g, aw_be,
                                                      so_w2, so_b2, aw_w2, aw_b2, v16,
                                                      op_w, op_b, out);
}

// Round 10
// 220.498 us; speedup vs baseline: 2.0723x; 1.0331x over previous
//
#include <hip/hip_runtime.h>
#include <hip/hip_fp16.h>
#include <cstdint>
#include <cstddef>

#define B_ 4
#define C_ 128
#define H_ 128
#define W_ 128
#define P_ (H_*W_)       // 16384
#define NH_ 8
#define NL_ 3
#define NP_ 4
#define HD_ 16
#define C2_ 64
#define ST_ 136          // bf16 LDS row stride (shorts) = 68 words: even 8/bank b128 access

// ---- workspace layout (float elements) ----
#define SZ_V      ((size_t)B_*NL_*P_*C_)
#define OFF_V     ((size_t)0)
#define OFF_HID   (OFF_V + SZ_V)
#define SZ_HID    ((size_t)2*B_*C2_*P_)
#define OFF_ST    (OFF_HID + SZ_HID)
#define SZ_ST     ((size_t)128)
#define OFF_BE    (OFF_ST + SZ_ST)
#define SZ_BE     ((size_t)(NL_*C_))

typedef short bf16x8 __attribute__((ext_vector_type(8)));
typedef float f32x4  __attribute__((ext_vector_type(4)));
#define MFMA16(a,b,c) __builtin_amdgcn_mfma_f32_16x16x32_bf16(a,b,c,0,0,0)

// split fp32 -> bf16 hi + bf16 lo (truncation; rem exact)
__device__ __forceinline__ void cvt8(const float* __restrict__ x, bf16x8& hi, bf16x8& lo) {
#pragma unroll
    for (int j = 0; j < 8; ++j) {
        unsigned ub = __float_as_uint(x[j]);
        hi[j] = (short)(ub >> 16);
        float rem = x[j] - __uint_as_float(ub & 0xffff0000u);
        lo[j] = (short)(__float_as_uint(rem) >> 16);
    }
}

__device__ __forceinline__ bf16x8 cvt8rn(const float* __restrict__ x) {
    bf16x8 r;
#pragma unroll
    for (int j = 0; j < 8; ++j) {
        unsigned u = __float_as_uint(x[j]);
        r[j] = (short)((u + 0x7fffu + ((u >> 16) & 1u)) >> 16);
    }
    return r;
}

__device__ __forceinline__ unsigned short f2bf_rn(float f) {
    unsigned u = __float_as_uint(f);
    return (unsigned short)((u + 0x7fffu + ((u >> 16) & 1u)) >> 16);
}
__device__ __forceinline__ unsigned pkbf2(float a, float b) {
    return (unsigned)f2bf_rn(a) | ((unsigned)f2bf_rn(b) << 16);
}
__device__ __forceinline__ float bflo(unsigned u) { return __uint_as_float(u << 16); }
__device__ __forceinline__ float bfhi(unsigned u) { return __uint_as_float(u & 0xffff0000u); }

__device__ __forceinline__ unsigned pkhalf2(float a, float b) {
    return (unsigned)__half_as_ushort(__float2half_rn(a))
         | ((unsigned)__half_as_ushort(__float2half_rn(b)) << 16);
}
__device__ __forceinline__ float hlo(unsigned u) { return __half2float(__ushort_as_half((unsigned short)u)); }
__device__ __forceinline__ float hhi(unsigned u) { return __half2float(__ushort_as_half((unsigned short)(u >> 16))); }

// ---------------------------------------------------------------------------
__global__ void k_prep(const float* __restrict__ vp_w, const float* __restrict__ vp_b,
                       const float* __restrict__ le, float* __restrict__ bias_eff,
                       float* __restrict__ stats)
{
    const int t = threadIdx.x;            // 384 threads
    if (t < 128) stats[t] = 0.f;
    const int l = t >> 7;
    const int o = t & 127;
    float d = vp_b[o];
    for (int k = 0; k < 128; ++k) d = fmaf(vp_w[o*128 + k], le[l*128 + k], d);
    bias_eff[l*128 + o] = d;
}

// ---------------------------------------------------------------------------
// MFMA value projection -> bf16 head-planar v [b][l][h][p][hd].
// Transposed bf16 LDS tile [64px][ST_]; compute: 1 ds_read_b128 + 2 MFMA per step.
__global__ __launch_bounds__(256) void k_vproj(
    const float* __restrict__ vals, const float* __restrict__ vp_w,
    const float* __restrict__ bias_eff, unsigned short* __restrict__ v16)
{
    __shared__ unsigned short S2[64*ST_];     // 17408 B
    const int tid = threadIdx.x;
    const int wv = tid >> 6, l = tid & 63;
    const int lr = l & 15, lg = l >> 4;
    const int bl = blockIdx.y, lvl = bl % NL_;
    const int px0 = blockIdx.x * 64;
    const float* __restrict__ X = vals + (size_t)bl*C_*P_;

    bf16x8 Ahi[2][4], Alo[2][4];
#pragma unroll
    for (int rt = 0; rt < 2; ++rt)
#pragma unroll
        for (int t = 0; t < 4; ++t) {
            const float* wr = vp_w + (size_t)(wv*32 + rt*16 + lr)*128 + t*32 + lg*8;
            float x8[8];
            float4 a = *(const float4*)wr, b = *(const float4*)(wr + 4);
            x8[0]=a.x; x8[1]=a.y; x8[2]=a.z; x8[3]=a.w;
            x8[4]=b.x; x8[5]=b.y; x8[6]=b.z; x8[7]=b.w;
            cvt8(x8, Ahi[rt][t], Alo[rt][t]);
        }

    // stage: thread px = tid&63, ch block = (tid>>6)*32; fp32 -> bf16 once
    {
        const int pxl = tid & 63, chb = (tid >> 6) * 32;
        const float* xp = X + (size_t)chb*P_ + px0 + pxl;
        unsigned w[16];
#pragma unroll
        for (int j = 0; j < 16; ++j)
            w[j] = pkbf2(xp[(size_t)(2*j)*P_], xp[(size_t)(2*j+1)*P_]);
        uint4* dst = (uint4*)&S2[pxl*ST_ + chb];
        dst[0] = make_uint4(w[0],w[1],w[2],w[3]);
        dst[1] = make_uint4(w[4],w[5],w[6],w[7]);
        dst[2] = make_uint4(w[8],w[9],w[10],w[11]);
        dst[3] = make_uint4(w[12],w[13],w[14],w[15]);
    }
    __syncthreads();

    f32x4 acc[2][4];
#pragma unroll
    for (int rt = 0; rt < 2; ++rt)
#pragma unroll
        for (int c = 0; c < 4; ++c)
#pragma unroll
            for (int r = 0; r < 4; ++r) acc[rt][c][r] = 0.f;

#pragma unroll
    for (int s = 0; s < 16; ++s) {
        const int c = s >> 2, t = s & 3;
        bf16x8 bb = *(const bf16x8*)&S2[(c*16 + lr)*ST_ + t*32 + lg*8];
#pragma unroll
        for (int rt = 0; rt < 2; ++rt) {
            acc[rt][c] = MFMA16(Ahi[rt][t], bb, acc[rt][c]);
            acc[rt][c] = MFMA16(Alo[rt][t], bb, acc[rt][c]);
        }
    }

    const float* be = bias_eff + lvl*128;
#pragma unroll
    for (int c = 0; c < 4; ++c) {
        const int px = px0 + c*16 + lr;
#pragma unroll
        for (int rt = 0; rt < 2; ++rt) {
            const int h  = wv*2 + rt;
            const int oc = h*16 + lg*4;
            uint2 stv;
            stv.x = pkbf2(acc[rt][c][0] + be[oc+0], acc[rt][c][1] + be[oc+1]);
            stv.y = pkbf2(acc[rt][c][2] + be[oc+2], acc[rt][c][3] + be[oc+3]);
            *(uint2*)(v16 + (((size_t)bl*NH_ + h)*P_ + px)*16 + lg*4) = stv;
        }
    }
}

// ---------------------------------------------------------------------------
// MFMA conv1 (both branches): transposed bf16 LDS tile; + GN stats.
__global__ __launch_bounds__(256) void k_conv1(
    const float* __restrict__ q,
    const float* __restrict__ w_so, const float* __restrict__ b_so,
    const float* __restrict__ w_aw, const float* __restrict__ b_aw,
    float* __restrict__ hid, float* __restrict__ stats)
{
    __shared__ unsigned short S2[64*ST_];
    const int tid = threadIdx.x;
    const int wv = tid >> 6, l = tid & 63;
    const int lr = l & 15, lg = l >> 4;
    const int b = blockIdx.y;
    const int br = wv >> 1, oc0 = (wv & 1) * 32;
    const float* __restrict__ W  = br ? w_aw : w_so;
    const float* __restrict__ bi = br ? b_aw : b_so;
    const float* __restrict__ X  = q + (size_t)b*C_*P_;
    const int px0 = blockIdx.x * 64;

    bf16x8 Ahi[2][4], Alo[2][4];
#pragma unroll
    for (int rt = 0; rt < 2; ++rt)
#pragma unroll
        for (int t = 0; t < 4; ++t) {
            const float* wr = W + (size_t)(oc0 + rt*16 + lr)*128 + t*32 + lg*8;
            float x8[8];
            float4 a = *(const float4*)wr, bb = *(const float4*)(wr + 4);
            x8[0]=a.x; x8[1]=a.y; x8[2]=a.z; x8[3]=a.w;
            x8[4]=bb.x; x8[5]=bb.y; x8[6]=bb.z; x8[7]=bb.w;
            cvt8(x8, Ahi[rt][t], Alo[rt][t]);
        }

    {
        const int pxl = tid & 63, chb = (tid >> 6) * 32;
        const float* xp = X + (size_t)chb*P_ + px0 + pxl;
        unsigned w[16];
#pragma unroll
        for (int j = 0; j < 16; ++j)
            w[j] = pkbf2(xp[(size_t)(2*j)*P_], xp[(size_t)(2*j+1)*P_]);
        uint4* dst = (uint4*)&S2[pxl*ST_ + chb];
        dst[0] = make_uint4(w[0],w[1],w[2],w[3]);
        dst[1] = make_uint4(w[4],w[5],w[6],w[7]);
        dst[2] = make_uint4(w[8],w[9],w[10],w[11]);
        dst[3] = make_uint4(w[12],w[13],w[14],w[15]);
    }
    __syncthreads();

    f32x4 acc[2][4];
#pragma unroll
    for (int rt = 0; rt < 2; ++rt)
#pragma unroll
        for (int c = 0; c < 4; ++c)
#pragma unroll
            for (int r = 0; r < 4; ++r) acc[rt][c][r] = 0.f;

#pragma unroll
    for (int s = 0; s < 16; ++s) {
        const int c = s >> 2, t = s & 3;
        bf16x8 bb = *(const bf16x8*)&S2[(c*16 + lr)*ST_ + t*32 + lg*8];
#pragma unroll
        for (int rt = 0; rt < 2; ++rt) {
            acc[rt][c] = MFMA16(Ahi[rt][t], bb, acc[rt][c]);
            acc[rt][c] = MFMA16(Alo[rt][t], bb, acc[rt][c]);
        }
    }

    float* hb = hid + ((size_t)(br*B_ + b)*C2_)*P_;
#pragma unroll
    for (int rt = 0; rt < 2; ++rt) {
        float s = 0.f, ss = 0.f;
#pragma unroll
        for (int c = 0; c < 4; ++c) {
            const int px = px0 + c*16 + lr;
#pragma unroll
            for (int r = 0; r < 4; ++r) {
                const int oc = oc0 + rt*16 + lg*4 + r;
                float v = acc[rt][c][r] + bi[oc];
                hb[(size_t)oc*P_ + px] = v;
                s += v; ss += v*v;
            }
        }
#pragma unroll
        for (int off = 16; off > 0; off >>= 1) {
            s  += __shfl_xor(s,  off, 64);
            ss += __shfl_xor(ss, off, 64);
        }
        if ((l & 31) == 0) {
            const int g = (oc0 + rt*16 + (l >> 4)*4) >> 3;
            atomicAdd(&stats[((br*B_ + b)*8 + g)*2 + 0], s);
            atomicAdd(&stats[((br*B_ + b)*8 + g)*2 + 1], ss);
        }
    }
}

// ---------------------------------------------------------------------------
// FUSED conv2 + sampling + final conv. Phase1: 2-MFMA (B single bf16-RN);
// Phase2: gather -> bf16 OUT tile; Phase3: b128-read B + 2 MFMA -> global.
__global__ __launch_bounds__(256) void k_conv2s(
    const float* __restrict__ hid, const float* __restrict__ stats,
    const float* __restrict__ so_g, const float* __restrict__ so_be,
    const float* __restrict__ aw_g, const float* __restrict__ aw_be,
    const float* __restrict__ so_w2, const float* __restrict__ so_b2,
    const float* __restrict__ aw_w2, const float* __restrict__ aw_b2,
    const unsigned short* __restrict__ v16,
    const float* __restrict__ op_w, const float* __restrict__ op_b,
    float* __restrict__ outg)
{
    __shared__ float sc[2][64], sh[2][64];
    __shared__ unsigned SAB[96*66 + 48*66];   // phase1/2: SA16+SB16; phase3: OUTB[64][ST_] bf16
    unsigned* SA16 = SAB;
    unsigned* SB16 = SAB + 96*66;
    unsigned short* OUTB = (unsigned short*)SAB;
    const int tid = threadIdx.x;
    const int wv = tid >> 6, l = tid & 63;
    const int lr = l & 15, lg = l >> 4;

    const int lid = blockIdx.x + 256*blockIdx.y;
    const int swz = ((lid & 7) << 7) | (lid >> 3);
    const int b    = swz >> 8;
    const int tile = swz & 255;
    const int x0 = (tile & 7) * 16;
    const int y0 = (tile >> 3) * 4;

    if (tid < 128) {
        const int br = tid >> 6, c = tid & 63, g = c >> 3;
        const float ninv = 1.f/(8.f*(float)P_);
        float s  = stats[((br*B_ + b)*8 + g)*2 + 0];
        float ss = stats[((br*B_ + b)*8 + g)*2 + 1];
        float mu  = s*ninv;
        float var = ss*ninv - mu*mu;
        float rs  = rsqrtf(var + 1e-5f);
        float ga = br ? aw_g[c]  : so_g[c];
        float be = br ? aw_be[c] : so_be[c];
        sc[br][c] = ga*rs;
        sh[br][c] = be - mu*ga*rs;
    }
    __syncthreads();

    const int pxw = (y0 + wv)*W_ + x0 + lr;

    // ---- phase 1a: offset branch 192 ch -> SA16 ----
    bf16x8 Bv[2];
    {
        const float* hs = hid + ((size_t)(0*B_ + b)*C2_)*P_ + pxw;
#pragma unroll
        for (int t = 0; t < 2; ++t) {
            float x8[8];
#pragma unroll
            for (int j = 0; j < 8; ++j) {
                const int k = t*32 + lg*8 + j;
                x8[j] = fmaxf(fmaf(hs[(size_t)k*P_], sc[0][k], sh[0][k]), 0.f);
            }
            Bv[t] = cvt8rn(x8);
        }
    }
#pragma unroll
    for (int tile2 = 0; tile2 < 12; ++tile2) {
        f32x4 acc; acc[0]=0.f; acc[1]=0.f; acc[2]=0.f; acc[3]=0.f;
#pragma unroll
        for (int t = 0; t < 2; ++t) {
            const float* wr = so_w2 + (size_t)(tile2*16 + lr)*64 + t*32 + lg*8;
            float x8[8];
            float4 a = *(const float4*)wr, bb = *(const float4*)(wr + 4);
            x8[0]=a.x; x8[1]=a.y; x8[2]=a.z; x8[3]=a.w;
            x8[4]=bb.x; x8[5]=bb.y; x8[6]=bb.z; x8[7]=bb.w;
            bf16x8 ahi, alo; cvt8(x8, ahi, alo);
            acc = MFMA16(ahi, Bv[t], acc);
            acc = MFMA16(alo, Bv[t], acc);
        }
#pragma unroll
        for (int rp = 0; rp < 2; ++rp) {
            const int ch = tile2*16 + lg*4 + 2*rp;
            SA16[(tile2*8 + lg*2 + rp)*66 + wv*16 + lr] =
                pkhalf2(acc[2*rp] + so_b2[ch], acc[2*rp+1] + so_b2[ch+1]);
        }
    }

    // ---- phase 1b: attn branch 96 ch -> SB16 ----
    {
        const float* hs = hid + ((size_t)(1*B_ + b)*C2_)*P_ + pxw;
#pragma unroll
        for (int t = 0; t < 2; ++t) {
            float x8[8];
#pragma unroll
            for (int j = 0; j < 8; ++j) {
                const int k = t*32 + lg*8 + j;
                x8[j] = fmaxf(fmaf(hs[(size_t)k*P_], sc[1][k], sh[1][k]), 0.f);
            }
            Bv[t] = cvt8rn(x8);
        }
    }
#pragma unroll
    for (int tile2 = 0; tile2 < 6; ++tile2) {
        f32x4 acc; acc[0]=0.f; acc[1]=0.f; acc[2]=0.f; acc[3]=0.f;
#pragma unroll
        for (int t = 0; t < 2; ++t) {
            const float* wr = aw_w2 + (size_t)(tile2*16 + lr)*64 + t*32 + lg*8;
            float x8[8];
            float4 a = *(const float4*)wr, bb = *(const float4*)(wr + 4);
            x8[0]=a.x; x8[1]=a.y; x8[2]=a.z; x8[3]=a.w;
            x8[4]=bb.x; x8[5]=bb.y; x8[6]=bb.z; x8[7]=bb.w;
            bf16x8 ahi, alo; cvt8(x8, ahi, alo);
            acc = MFMA16(ahi, Bv[t], acc);
            acc = MFMA16(alo, Bv[t], acc);
        }
#pragma unroll
        for (int rp = 0; rp < 2; ++rp) {
            const int ch = tile2*16 + lg*4 + 2*rp;
            SB16[(tile2*8 + lg*2 + rp)*66 + wv*16 + lr] =
                pkhalf2(acc[2*rp] + aw_b2[ch], acc[2*rp+1] + aw_b2[ch+1]);
        }
    }
    __syncthreads();

    // ---- phase 2: preload meta (SAB gets overwritten), then gather ----
    const int hh  = tid >> 5;
    const int pl0 = (tid & 31) * 2;

    unsigned off12[2][12];
    float    aw12[2][12];
#pragma unroll
    for (int up = 0; up < 2; ++up) {
        const int pl = pl0 + up;
        float av[12];
#pragma unroll
        for (int k = 0; k < 6; ++k) {
            const unsigned w = SB16[(hh*6 + k)*66 + pl];
            av[2*k]   = hlo(w);
            av[2*k+1] = hhi(w);
        }
        float m = av[0];
#pragma unroll
        for (int s = 1; s < 12; ++s) m = fmaxf(m, av[s]);
        float sum = 0.f;
#pragma unroll
        for (int s = 0; s < 12; ++s) { av[s] = __expf(av[s]-m); sum += av[s]; }
        const float inv = 1.f/sum;
#pragma unroll
        for (int s = 0; s < 12; ++s) aw12[up][s] = av[s]*inv;
#pragma unroll
        for (int s = 0; s < 12; ++s) off12[up][s] = SA16[(hh*12 + s)*66 + pl];
    }
    __syncthreads();   // SAB is now OUTB

#pragma unroll
    for (int up = 0; up < 2; ++up) {
        const int pl = pl0 + up;
        const int x  = x0 + (pl & 15);
        const int y  = y0 + (pl >> 4);
        const float refx = (float)x * (1.f/(float)(W_-1));
        const float refy = (float)y * (1.f/(float)(H_-1));

        float acc[16];
#pragma unroll
        for (int j = 0; j < 16; ++j) acc[j] = 0.f;

#pragma unroll
        for (int lv = 0; lv < NL_; ++lv) {
            const unsigned short* vb = v16 + (((size_t)(b*NL_ + lv)*NH_ + hh)*P_)*16;
#pragma unroll
            for (int pt = 0; pt < NP_; ++pt) {
                const int s = lv*4 + pt;
                const float ox = hlo(off12[up][s]), oy = hhi(off12[up][s]);
                float lx2 = fminf(fmaxf(refx + ox*(1.f/(float)W_), 0.f), 1.f);
                float ly2 = fminf(fmaxf(refy + oy*(1.f/(float)H_), 0.f), 1.f);
                float px = fminf(fmaxf(lx2*(float)W_ - 0.5f, 0.f), (float)(W_-1));
                float py = fminf(fmaxf(ly2*(float)H_ - 0.5f, 0.f), (float)(H_-1));
                float x0f = floorf(px), y0f = floorf(py);
                float wx = px - x0f, wy = py - y0f;
                int xi0 = (int)x0f, yi0 = (int)y0f;
                int xi1 = min(xi0+1, W_-1), yi1 = min(yi0+1, H_-1);
                const uint4* t00 = (const uint4*)(vb + (size_t)(yi0*W_ + xi0)*16);
                const uint4* t01 = (const uint4*)(vb + (size_t)(yi0*W_ + xi1)*16);
                const uint4* t10 = (const uint4*)(vb + (size_t)(yi1*W_ + xi0)*16);
                const uint4* t11 = (const uint4*)(vb + (size_t)(yi1*W_ + xi1)*16);
                uint4 q00a = t00[0], q00b = t00[1];
                uint4 q01a = t01[0], q01b = t01[1];
                uint4 q10a = t10[0], q10b = t10[1];
                uint4 q11a = t11[0], q11b = t11[1];
                const float a   = aw12[up][s];
                const float a11 = a*wx*wy;
                const float a10 = a*wy - a11;
                const float a01 = a*wx - a11;
                const float a00 = a - a01 - a10 - a11;
                const unsigned* u00 = (const unsigned*)&q00a;
                const unsigned* u01 = (const unsigned*)&q01a;
                const unsigned* u10 = (const unsigned*)&q10a;
                const unsigned* u11 = (const unsigned*)&q11a;
#pragma unroll
                for (int i = 0; i < 4; ++i) {
                    float r = acc[2*i];
                    r = fmaf(a00, bflo(u00[i]), r);
                    r = fmaf(a01, bflo(u01[i]), r);
                    r = fmaf(a10, bflo(u10[i]), r);
                    r = fmaf(a11, bflo(u11[i]), r);
                    acc[2*i] = r;
                    r = acc[2*i+1];
                    r = fmaf(a00, bfhi(u00[i]), r);
                    r = fmaf(a01, bfhi(u01[i]), r);
                    r = fmaf(a10, bfhi(u10[i]), r);
                    r = fmaf(a11, bfhi(u11[i]), r);
                    acc[2*i+1] = r;
                }
                const unsigned* v00 = (const unsigned*)&q00b;
                const unsigned* v01 = (const unsigned*)&q01b;
                const unsigned* v10 = (const unsigned*)&q10b;
                const unsigned* v11 = (const unsigned*)&q11b;
#pragma unroll
                for (int i = 0; i < 4; ++i) {
                    float r = acc[8 + 2*i];
                    r = fmaf(a00, bflo(v00[i]), r);
                    r = fmaf(a01, bflo(v01[i]), r);
                    r = fmaf(a10, bflo(v10[i]), r);
                    r = fmaf(a11, bflo(v11[i]), r);
                    acc[8 + 2*i] = r;
                    r = acc[8 + 2*i + 1];
                    r = fmaf(a00, bfhi(v00[i]), r);
                    r = fmaf(a01, bfhi(v01[i]), r);
                    r = fmaf(a10, bfhi(v10[i]), r);
                    r = fmaf(a11, bfhi(v11[i]), r);
                    acc[8 + 2*i + 1] = r;
                }
            }
        }
        // pack acc -> bf16 OUT tile row pl, cols hh*16..+15
        unsigned w8[8];
#pragma unroll
        for (int i = 0; i < 8; ++i) w8[i] = pkbf2(acc[2*i], acc[2*i+1]);
        uint4* dst = (uint4*)&OUTB[pl*ST_ + hh*HD_];
        dst[0] = make_uint4(w8[0], w8[1], w8[2], w8[3]);
        dst[1] = make_uint4(w8[4], w8[5], w8[6], w8[7]);
    }
    __syncthreads();   // OUT tile complete

    // ---- phase 3: final conv from bf16 OUT tile -> global (channel-major) ----
    bf16x8 Ohi[2][4], Olo[2][4];
#pragma unroll
    for (int rt = 0; rt < 2; ++rt)
#pragma unroll
        for (int t = 0; t < 4; ++t) {
            const float* wr = op_w + (size_t)(wv*32 + rt*16 + lr)*128 + t*32 + lg*8;
            float x8[8];
            float4 a = *(const float4*)wr, bb = *(const float4*)(wr + 4);
            x8[0]=a.x; x8[1]=a.y; x8[2]=a.z; x8[3]=a.w;
            x8[4]=bb.x; x8[5]=bb.y; x8[6]=bb.z; x8[7]=bb.w;
            cvt8(x8, Ohi[rt][t], Olo[rt][t]);
        }

    f32x4 oacc[2][4];
#pragma unroll
    for (int rt = 0; rt < 2; ++rt)
#pragma unroll
        for (int c = 0; c < 4; ++c)
#pragma unroll
            for (int r = 0; r < 4; ++r) oacc[rt][c][r] = 0.f;

#pragma unroll
    for (int s = 0; s < 16; ++s) {
        const int c = s >> 2, t = s & 3;
        bf16x8 bb = *(const bf16x8*)&OUTB[(c*16 + lr)*ST_ + t*32 + lg*8];
#pragma unroll
        for (int rt = 0; rt < 2; ++rt) {
            oacc[rt][c] = MFMA16(Ohi[rt][t], bb, oacc[rt][c]);
            oacc[rt][c] = MFMA16(Olo[rt][t], bb, oacc[rt][c]);
        }
    }

    float* ob = outg + (size_t)b*C_*P_;
#pragma unroll
    for (int rt = 0; rt < 2; ++rt)
#pragma unroll
        for (int c = 0; c < 4; ++c) {
            const int p = (y0 + c)*W_ + x0 + lr;
#pragma unroll
            for (int r = 0; r < 4; ++r) {
                const int oc = wv*32 + rt*16 + lg*4 + r;
                ob[(size_t)oc*P_ + p] = oacc[rt][c][r] + op_b[oc];
            }
        }
}

// ---------------------------------------------------------------------------
extern "C" void kernel_launch(void* const* d_in, const int* in_sizes, int n_in,
                              void* d_out, int out_size, void* d_ws, size_t ws_size,
                              hipStream_t stream)
{
    const float* query = (const float*)d_in[0];
    // d_in[1] = keys : UNUSED by reference
    const float* values = (const float*)d_in[2];
    const float* so_w1 = (const float*)d_in[3];
    const float* so_b1 = (const float*)d_in[4];
    const float* so_g  = (const float*)d_in[5];
    const float* so_be = (const float*)d_in[6];
    const float* so_w2 = (const float*)d_in[7];
    const float* so_b2 = (const float*)d_in[8];
    const float* aw_w1 = (const float*)d_in[9];
    const float* aw_b1 = (const float*)d_in[10];
    const float* aw_g  = (const float*)d_in[11];
    const float* aw_be = (const float*)d_in[12];
    const float* aw_w2 = (const float*)d_in[13];
    const float* aw_b2 = (const float*)d_in[14];
    const float* vp_w  = (const float*)d_in[15];
    const float* vp_b  = (const float*)d_in[16];
    const float* op_w  = (const float*)d_in[17];
    const float* op_b  = (const float*)d_in[18];
    const float* le    = (const float*)d_in[19];

    float* ws      = (float*)d_ws;
    unsigned short* v16 = (unsigned short*)(ws + OFF_V);
    float* hid     = ws + OFF_HID;
    float* stats   = ws + OFF_ST;
    float* be      = ws + OFF_BE;
    float* out     = (float*)d_out;

    k_prep<<<dim3(1), dim3(384), 0, stream>>>(vp_w, vp_b, le, be, stats);
    k_vproj<<<dim3(P_/64, B_*NL_), dim3(256), 0, stream>>>(values, vp_w, be, v16);
    k_conv1<<<dim3(P_/64, B_), dim3(256), 0, stream>>>(query, so_w1, so_b1, aw_w1, aw_b1, hid, stats);
    k_conv2s<<<dim3(256, B_), dim3(256), 0, stream>>>(hid, stats, so_g, so_be, aw_g, aw_be,
                                                      so_w2, so_b2, aw_w2, aw_b2, v16,
                                                      op_w, op_b, out);
}